// Round 5
// baseline (13109.450 us; speedup 1.0000x reference)
//
#include <hip/hip_runtime.h>
#include <hip/hip_bf16.h>
#include <math.h>

#define SEQ 1024
#define HID 512
#define FOURH 2048
#define IND 400
#define NT 13

#define NWG_DIR 16
#define LSTM_THREADS 1024
#define JPW 32      // hidden units per WG
#define WCOLS 128   // gate columns per WG (4 gates * 32 j)

__device__ __forceinline__ float bf2f(unsigned short u) {
    union { unsigned u32; float f; } v;
    v.u32 = ((unsigned)u) << 16;
    return v.f;
}

__device__ __forceinline__ unsigned short f2bf(float f) {
    union { float f; unsigned u; } v;
    v.f = f;
    unsigned u = v.u;
    unsigned rounding = 0x7FFFu + ((u >> 16) & 1u);
    u += rounding;
    return (unsigned short)(u >> 16);
}

// dtype-agnostic float load: isf32 selects f32 vs bf16 interpretation
__device__ __forceinline__ float ldf(const void* p, size_t i, int isf32) {
    return isf32 ? ((const float*)p)[i] : bf2f(((const unsigned short*)p)[i]);
}

__device__ __forceinline__ float sigm(float x) { return 1.0f / (1.0f + expf(-x)); }
// saturating clamp: numerically identical for |z|<60 (sigm/tanh saturated beyond),
// and fminf/fmaxf squash NaN -> LSTM output provably finite.
__device__ __forceinline__ float satz(float z) { return fminf(fmaxf(z, -60.f), 60.f); }

// ---------------------------------------------------------------- input dtype detection
// For a true bf16 array, element u16s have exponent fields clustered in [90,127)
// (values ~N(0,0.05)). For f32 data read as u16 pairs, the LOW halves are random
// mantissa bits -> ~14% land in that band. Majority vote over 256 low-halves.
__global__ __launch_bounds__(64) void detect_kernel(const unsigned short* __restrict__ w,
                                                    int* __restrict__ flag) {
    int lane = threadIdx.x;
    int cnt = 0;
    for (int i = 0; i < 4; ++i) {
        unsigned short u = w[2 * (lane * 4 + i)];   // low half if buffer is f32
        int e = (u >> 7) & 0xFF;
        if (e >= 90 && e < 127) cnt++;
    }
#pragma unroll
    for (int off = 32; off >= 1; off >>= 1) cnt += __shfl_xor(cnt, off, 64);
    if (lane == 0) *flag = (cnt < 128) ? 1 : 0;    // 1 => inputs are float32
}

// ---------------------------------------------------------------- embedding
__global__ void embed_kernel(const int* __restrict__ x, const int* __restrict__ cas,
                             const int* __restrict__ pos,
                             const void* __restrict__ W_emb,
                             const void* __restrict__ W_cas,
                             const void* __restrict__ W_pos,
                             float* __restrict__ feat, const int* __restrict__ dflag) {
    const int isf32 = *dflag;
    int t = blockIdx.x;
    int xi = x[t], ci = cas[t], pi = pos[t];
    for (int e = threadIdx.x; e < IND; e += blockDim.x) {
        float v;
        if (e < 300)      v = ldf(W_emb, (size_t)xi * 300 + e, isf32);
        else if (e < 350) v = ldf(W_cas, (size_t)ci * 50 + (e - 300), isf32);
        else              v = ldf(W_pos, (size_t)pi * 50 + (e - 350), isf32);
        feat[t * IND + e] = v;
    }
}

// ---------------------------------------------------------------- pre = feat @ Wx + b (both dirs), bf16 out
__global__ __launch_bounds__(256) void pre_gemm_kernel(const float* __restrict__ feat,
        const void* __restrict__ Wx_f, const void* __restrict__ b_f,
        const void* __restrict__ Wx_b, const void* __restrict__ b_b,
        unsigned short* __restrict__ pre, const int* __restrict__ dflag) {
    __shared__ float ftile[16 * IND];
    const int isf32 = *dflag;
    int dir = blockIdx.z;
    const void* Wx = dir ? Wx_b : Wx_f;
    const void* bb = dir ? b_b : b_f;
    unsigned short* pre_d = pre + (size_t)dir * SEQ * FOURH;
    int r0 = blockIdx.y * 16;
    int col = blockIdx.x * 256 + threadIdx.x;

    for (int idx = threadIdx.x; idx < 16 * IND; idx += 256) {
        int r = idx / IND;
        int k = idx - r * IND;
        ftile[idx] = feat[(size_t)(r0 + r) * IND + k];
    }
    __syncthreads();

    float acc[16];
    float bias = ldf(bb, col, isf32);
#pragma unroll
    for (int r = 0; r < 16; ++r) acc[r] = bias;

    for (int kk = 0; kk < 100; ++kk) {
        int k = kk * 4;
        float w0 = ldf(Wx, (size_t)(k + 0) * FOURH + col, isf32);
        float w1 = ldf(Wx, (size_t)(k + 1) * FOURH + col, isf32);
        float w2 = ldf(Wx, (size_t)(k + 2) * FOURH + col, isf32);
        float w3 = ldf(Wx, (size_t)(k + 3) * FOURH + col, isf32);
#pragma unroll
        for (int r = 0; r < 16; ++r) {
            float4 f = *(const float4*)&ftile[r * IND + k];
            acc[r] += f.x * w0 + f.y * w1 + f.z * w2 + f.w * w3;
        }
    }
    for (int r = 0; r < 16; ++r) pre_d[(size_t)(r0 + r) * FOURH + col] = f2bf(acc[r]);
}

// ---------------------------------------------------------------- persistent bidirectional LSTM
// 32 WGs (16/dir), 1024 threads. Wh slice (512x128) lives in REGISTERS:
// thread (seg,col) holds Wh[seg*64 .. seg*64+63][gcol] as 64 f32.
__global__ __launch_bounds__(LSTM_THREADS, 4) void lstm_kernel(
        const void* __restrict__ Wh_f, const void* __restrict__ Wh_b,
        const void* __restrict__ h0, const void* __restrict__ c0,
        const unsigned short* __restrict__ pre, float* __restrict__ hsout,
        float* hbuf, unsigned* syncc, const int* __restrict__ dflag) {
    __shared__ float hs[HID];            // broadcast h for this step
    __shared__ float red[8 * WCOLS];     // per-seg partial dots
    __shared__ float zb[WCOLS];          // pre (input projection) values
    __shared__ float cb[JPW];            // cell state

    const int isf32 = *dflag;
    const int tid = threadIdx.x;
    const int b = blockIdx.x;
    const int dir = b & 1;
    const int g = b >> 1;            // 0..15
    const int j0 = g * JPW;

    const void* Wh = dir ? Wh_b : Wh_f;
    const unsigned short* pre_d = pre + (size_t)dir * SEQ * FOURH;
    float* hso = hsout + (size_t)dir * SEQ * HID;
    float* hb_d = hbuf + dir * 2 * HID;
    unsigned* cnt = syncc + dir * 32;   // separate cache lines per direction

    const int col = tid & (WCOLS - 1);
    const int seg = tid >> 7;           // 0..7, each covers 64 k's
    const int gcol = (col >> 5) * HID + j0 + (col & 31);

    // ---- stage this thread's 64 Wh values into registers (dtype-branched, cold) ----
    float wreg[64];
    if (isf32) {
        const float* wp = (const float*)Wh + (size_t)(seg * 64) * FOURH + gcol;
#pragma unroll
        for (int kk = 0; kk < 64; ++kk) wreg[kk] = wp[(size_t)kk * FOURH];
    } else {
        const unsigned short* wp = (const unsigned short*)Wh + (size_t)(seg * 64) * FOURH + gcol;
#pragma unroll
        for (int kk = 0; kk < 64; ++kk) wreg[kk] = bf2f(wp[(size_t)kk * FOURH]);
    }

    if (tid < JPW) cb[tid] = ldf(c0, dir * HID + j0 + tid, isf32);
    // init ONLY parity 0 with h0 (identical values from all WGs: benign).
    // parity 1 is first read at s=1, after barrier 0 orders all step-0 writes.
    if (tid < HID)
        __hip_atomic_store(&hb_d[tid], ldf(h0, dir * HID + tid, isf32),
                           __ATOMIC_RELAXED, __HIP_MEMORY_SCOPE_AGENT);
    __syncthreads();

    for (int s = 0; s < SEQ; ++s) {
        const int t = dir ? (SEQ - 1 - s) : s;

        if (tid < HID)
            hs[tid] = __hip_atomic_load(&hb_d[(s & 1) * HID + tid],
                                        __ATOMIC_RELAXED, __HIP_MEMORY_SCOPE_AGENT);
        if (tid < WCOLS)
            zb[tid] = bf2f(pre_d[(size_t)t * FOURH + ((tid >> 5) * HID + j0 + (tid & 31))]);
        __syncthreads();

        // ---- matvec: acc = sum_k hs[seg*64+k] * wreg[k] ----
        float a0 = 0.f, a1 = 0.f, a2 = 0.f, a3 = 0.f;
        const float4* hp = (const float4*)(hs + seg * 64);
#pragma unroll
        for (int q = 0; q < 4; ++q) {
#pragma unroll
            for (int r = 0; r < 4; ++r) {
                float4 h4 = hp[q * 4 + r];
                int base = (q * 4 + r) * 4;
                if (r == 0) a0 += h4.x * wreg[base] + h4.y * wreg[base + 1] + h4.z * wreg[base + 2] + h4.w * wreg[base + 3];
                if (r == 1) a1 += h4.x * wreg[base] + h4.y * wreg[base + 1] + h4.z * wreg[base + 2] + h4.w * wreg[base + 3];
                if (r == 2) a2 += h4.x * wreg[base] + h4.y * wreg[base + 1] + h4.z * wreg[base + 2] + h4.w * wreg[base + 3];
                if (r == 3) a3 += h4.x * wreg[base] + h4.y * wreg[base + 1] + h4.z * wreg[base + 2] + h4.w * wreg[base + 3];
            }
        }
        red[seg * WCOLS + col] = (a0 + a1) + (a2 + a3);
        __syncthreads();

        if (tid < JPW) {
            int jj = tid;
            float z[4];
#pragma unroll
            for (int gt = 0; gt < 4; ++gt) {
                int c2 = gt * JPW + jj;
                float zt = zb[c2];
#pragma unroll
                for (int s8 = 0; s8 < 8; ++s8) zt += red[s8 * WCOLS + c2];
                z[gt] = satz(zt);
            }
            float cprev = cb[jj];
            float ig = sigm(z[0]);
            float fg = sigm(z[1]);
            float gg = tanhf(z[2]);
            float og = sigm(z[3]);
            float cnew = fg * cprev + ig * gg;
            cb[jj] = cnew;
            float hnew = og * tanhf(fminf(fmaxf(cnew, -60.f), 60.f));
            int jidx = j0 + jj;
            __hip_atomic_store(&hb_d[((s + 1) & 1) * HID + jidx], hnew,
                               __ATOMIC_RELAXED, __HIP_MEMORY_SCOPE_AGENT);
            hso[(size_t)t * HID + jidx] = hnew;
        }
        // ---- inter-WG barrier (16 WGs/direction, all co-resident) ----
        __syncthreads();   // all WG h-stores issued; vmcnt drained before s_barrier
        if (tid == 0)
            __hip_atomic_fetch_add(cnt, 1u, __ATOMIC_RELEASE, __HIP_MEMORY_SCOPE_AGENT);
        const unsigned target = (unsigned)(s + 1) * NWG_DIR;
        // EVERY thread acquires: its own post-barrier loads cannot be hoisted
        // above its own acquire observing the full count.
        while (__hip_atomic_load(cnt, __ATOMIC_ACQUIRE, __HIP_MEMORY_SCOPE_AGENT) < target)
            __builtin_amdgcn_s_sleep(2);
    }
}

// ---------------------------------------------------------------- out = concat(hf,hb)@W_out + b, log_softmax (f32 out)
__global__ __launch_bounds__(64) void outproj_kernel(const float* __restrict__ hsout,
        const void* __restrict__ W_out, const void* __restrict__ b_out,
        float* __restrict__ out_scores, const int* __restrict__ dflag) {
    const int isf32 = *dflag;
    int t = blockIdx.x;
    int lane = threadIdx.x;
    const float* hf = hsout + (size_t)t * HID;
    const float* hb = hsout + (size_t)SEQ * HID + (size_t)t * HID;
    float acc[NT];
#pragma unroll
    for (int j = 0; j < NT; ++j) acc[j] = 0.f;
    for (int k = lane; k < HID; k += 64) {
        float a = hf[k], b2 = hb[k];
#pragma unroll
        for (int j = 0; j < NT; ++j)
            acc[j] += a * ldf(W_out, (size_t)k * NT + j, isf32)
                    + b2 * ldf(W_out, (size_t)(HID + k) * NT + j, isf32);
    }
#pragma unroll
    for (int off = 32; off >= 1; off >>= 1) {
#pragma unroll
        for (int j = 0; j < NT; ++j) acc[j] += __shfl_xor(acc[j], off, 64);
    }
    float o[NT];
    float m = -1e30f;
#pragma unroll
    for (int j = 0; j < NT; ++j) { o[j] = acc[j] + ldf(b_out, j, isf32); m = fmaxf(m, o[j]); }
    float lse = 0.f;
#pragma unroll
    for (int j = 0; j < NT; ++j) lse += expf(o[j] - m);
    lse = m + logf(lse);
    if (lane < NT)
        out_scores[t * NT + lane] = o[lane] - lse;
}

// ---------------------------------------------------------------- Viterbi (single wave, lanes = tags; f32 path out)
__global__ __launch_bounds__(64) void viterbi_kernel(const float* __restrict__ em,
        const void* __restrict__ trans, const void* __restrict__ strans,
        const void* __restrict__ etrans, float* __restrict__ out_path,
        const int* __restrict__ dflag) {
    __shared__ unsigned char hist[SEQ][NT];
    const int isf32 = *dflag;
    int lane = threadIdx.x;
    int j = lane < NT ? lane : 0;
    float tr[NT];
#pragma unroll
    for (int i = 0; i < NT; ++i) tr[i] = ldf(trans, i * NT + j, isf32);
    float score = ldf(strans, j, isf32) + em[j];
    for (int t = 1; t < SEQ; ++t) {
        float pe = em[t * NT + j];          // independent of the shuffle chain
        float best = -1e30f;
        int arg = 0;
#pragma unroll
        for (int i = 0; i < NT; ++i) {
            float si = __shfl(score, i, 64);
            float cand = si + tr[i];
            if (cand > best) { best = cand; arg = i; }   // strict > == first-index tie-break
        }
        if (lane < NT) hist[t][lane] = (unsigned char)arg;
        score = best + pe;
    }
    score += ldf(etrans, j, isf32);
    float bmax = -1e30f;
    int last = 0;
#pragma unroll
    for (int i = 0; i < NT; ++i) {
        float si = __shfl(score, i, 64);
        if (si > bmax) { bmax = si; last = i; }
    }
    if (lane == 0) {
        int cur = last;
        out_path[SEQ - 1] = (float)cur;
        for (int t = SEQ - 1; t >= 1; --t) {
            cur = hist[t][cur];
            out_path[t - 1] = (float)cur;
        }
    }
}

// ---------------------------------------------------------------- launch
extern "C" void kernel_launch(void* const* d_in, const int* in_sizes, int n_in,
                              void* d_out, int out_size, void* d_ws, size_t ws_size,
                              hipStream_t stream) {
    const int* x      = (const int*)d_in[0];
    const int* casing = (const int*)d_in[1];
    const int* posi   = (const int*)d_in[2];
    const void* h0    = d_in[3];
    const void* c0    = d_in[4];
    const void* W_emb = d_in[5];
    const void* W_cas = d_in[6];
    const void* W_pos = d_in[7];
    const void* Wx_f  = d_in[8];
    const void* Wh_f  = d_in[9];
    const void* b_f   = d_in[10];
    const void* Wx_b  = d_in[11];
    const void* Wh_b  = d_in[12];
    const void* b_b   = d_in[13];
    const void* W_out = d_in[14];
    const void* b_out = d_in[15];
    const void* trans = d_in[16];
    const void* strans = d_in[17];
    const void* etrans = d_in[18];

    // workspace layout (~14.3 MB total)
    char* ws = (char*)d_ws;
    unsigned* syncc     = (unsigned*)ws;                          // counters at +0,+128; flag at +448
    int* dflag          = (int*)(ws + 448);
    float* feat         = (float*)(ws + 512);                     // 1024*400 f32 = 1,638,400
    unsigned short* pre = (unsigned short*)(ws + 1638912);        // 2*1024*2048 bf16 = 8,388,608
    float* hsout        = (float*)(ws + 10027520);                // 2*1024*512 f32 = 4,194,304
    float* hbuf         = (float*)(ws + 14221824);                // 2*2*512 f32 = 8,192

    // d_out is FLOAT32: 13312 tag_scores then 1024 path values
    float* out_scores = (float*)d_out;
    float* out_path   = out_scores + SEQ * NT;

    hipMemsetAsync(syncc, 0, 512, stream);

    detect_kernel<<<1, 64, 0, stream>>>((const unsigned short*)W_emb, dflag);

    embed_kernel<<<SEQ, 128, 0, stream>>>(x, casing, posi, W_emb, W_cas, W_pos, feat, dflag);

    dim3 g2(8, 64, 2);
    pre_gemm_kernel<<<g2, 256, 0, stream>>>(feat, Wx_f, b_f, Wx_b, b_b, pre, dflag);

    lstm_kernel<<<2 * NWG_DIR, LSTM_THREADS, 0, stream>>>(
        Wh_f, Wh_b, h0, c0, pre, hsout, hbuf, syncc, dflag);

    outproj_kernel<<<SEQ, 64, 0, stream>>>(hsout, W_out, b_out, out_scores, dflag);

    viterbi_kernel<<<1, 64, 0, stream>>>(out_scores, trans, strans, etrans, out_path, dflag);
}

// Round 6
// 3757.095 us; speedup vs baseline: 3.4893x; 3.4893x over previous
//
#include <hip/hip_runtime.h>
#include <hip/hip_bf16.h>
#include <math.h>

#define SEQ 1024
#define HID 512
#define FOURH 2048
#define IND 400
#define NT 13

#define NWG_DIR 16
#define LSTM_THREADS 1024
#define JPW 32      // hidden units per WG
#define WCOLS 128   // gate columns per WG (4 gates * 32 j)

__device__ __forceinline__ float bf2f(unsigned short u) {
    union { unsigned u32; float f; } v;
    v.u32 = ((unsigned)u) << 16;
    return v.f;
}

__device__ __forceinline__ unsigned short f2bf(float f) {
    union { float f; unsigned u; } v;
    v.f = f;
    unsigned u = v.u;
    unsigned rounding = 0x7FFFu + ((u >> 16) & 1u);
    u += rounding;
    return (unsigned short)(u >> 16);
}

// dtype-agnostic float load: isf32 selects f32 vs bf16 interpretation
__device__ __forceinline__ float ldf(const void* p, size_t i, int isf32) {
    return isf32 ? ((const float*)p)[i] : bf2f(((const unsigned short*)p)[i]);
}

__device__ __forceinline__ float sigm(float x) { return 1.0f / (1.0f + expf(-x)); }
// saturating clamp: numerically identical for |z|<60 (sigm/tanh saturated beyond),
// and fminf/fmaxf squash NaN -> LSTM output provably finite.
__device__ __forceinline__ float satz(float z) { return fminf(fmaxf(z, -60.f), 60.f); }

// ---------------------------------------------------------------- input dtype detection
__global__ __launch_bounds__(64) void detect_kernel(const unsigned short* __restrict__ w,
                                                    int* __restrict__ flag) {
    int lane = threadIdx.x;
    int cnt = 0;
    for (int i = 0; i < 4; ++i) {
        unsigned short u = w[2 * (lane * 4 + i)];   // low half if buffer is f32
        int e = (u >> 7) & 0xFF;
        if (e >= 90 && e < 127) cnt++;
    }
#pragma unroll
    for (int off = 32; off >= 1; off >>= 1) cnt += __shfl_xor(cnt, off, 64);
    if (lane == 0) *flag = (cnt < 128) ? 1 : 0;    // 1 => inputs are float32
}

// ---------------------------------------------------------------- embedding
__global__ void embed_kernel(const int* __restrict__ x, const int* __restrict__ cas,
                             const int* __restrict__ pos,
                             const void* __restrict__ W_emb,
                             const void* __restrict__ W_cas,
                             const void* __restrict__ W_pos,
                             float* __restrict__ feat, const int* __restrict__ dflag) {
    const int isf32 = *dflag;
    int t = blockIdx.x;
    int xi = x[t], ci = cas[t], pi = pos[t];
    for (int e = threadIdx.x; e < IND; e += blockDim.x) {
        float v;
        if (e < 300)      v = ldf(W_emb, (size_t)xi * 300 + e, isf32);
        else if (e < 350) v = ldf(W_cas, (size_t)ci * 50 + (e - 300), isf32);
        else              v = ldf(W_pos, (size_t)pi * 50 + (e - 350), isf32);
        feat[t * IND + e] = v;
    }
}

// ---------------------------------------------------------------- pre = feat @ Wx + b (both dirs), bf16 out
__global__ __launch_bounds__(256) void pre_gemm_kernel(const float* __restrict__ feat,
        const void* __restrict__ Wx_f, const void* __restrict__ b_f,
        const void* __restrict__ Wx_b, const void* __restrict__ b_b,
        unsigned short* __restrict__ pre, const int* __restrict__ dflag) {
    __shared__ float ftile[16 * IND];
    const int isf32 = *dflag;
    int dir = blockIdx.z;
    const void* Wx = dir ? Wx_b : Wx_f;
    const void* bb = dir ? b_b : b_f;
    unsigned short* pre_d = pre + (size_t)dir * SEQ * FOURH;
    int r0 = blockIdx.y * 16;
    int col = blockIdx.x * 256 + threadIdx.x;

    for (int idx = threadIdx.x; idx < 16 * IND; idx += 256) {
        int r = idx / IND;
        int k = idx - r * IND;
        ftile[idx] = feat[(size_t)(r0 + r) * IND + k];
    }
    __syncthreads();

    float acc[16];
    float bias = ldf(bb, col, isf32);
#pragma unroll
    for (int r = 0; r < 16; ++r) acc[r] = bias;

    for (int kk = 0; kk < 100; ++kk) {
        int k = kk * 4;
        float w0 = ldf(Wx, (size_t)(k + 0) * FOURH + col, isf32);
        float w1 = ldf(Wx, (size_t)(k + 1) * FOURH + col, isf32);
        float w2 = ldf(Wx, (size_t)(k + 2) * FOURH + col, isf32);
        float w3 = ldf(Wx, (size_t)(k + 3) * FOURH + col, isf32);
#pragma unroll
        for (int r = 0; r < 16; ++r) {
            float4 f = *(const float4*)&ftile[r * IND + k];
            acc[r] += f.x * w0 + f.y * w1 + f.z * w2 + f.w * w3;
        }
    }
    for (int r = 0; r < 16; ++r) pre_d[(size_t)(r0 + r) * FOURH + col] = f2bf(acc[r]);
}

// ---------------------------------------------------------------- persistent bidirectional LSTM
// 32 WGs (16/dir), 1024 threads. Wh slice (512x128) in REGISTERS (64 f32/thread).
// Cross-WG sync: single-spinner barrier (tid0 relaxed-spin on LLC counter,
// one agent release fence at arrival + one agent acquire fence at exit).
__global__ __launch_bounds__(LSTM_THREADS, 4) void lstm_kernel(
        const void* __restrict__ Wh_f, const void* __restrict__ Wh_b,
        const void* __restrict__ h0, const void* __restrict__ c0,
        const unsigned short* __restrict__ pre, float* __restrict__ hsout,
        float* hbuf, unsigned* syncc, const int* __restrict__ dflag) {
    __shared__ float hs[HID];            // broadcast h for this step
    __shared__ float red[8 * WCOLS];     // per-seg partial dots
    __shared__ float zb[WCOLS];          // pre (input projection) values
    __shared__ float cb[JPW];            // cell state

    const int isf32 = *dflag;
    const int tid = threadIdx.x;
    const int b = blockIdx.x;
    const int dir = b & 1;
    const int g = b >> 1;            // 0..15
    const int j0 = g * JPW;

    const void* Wh = dir ? Wh_b : Wh_f;
    const unsigned short* pre_d = pre + (size_t)dir * SEQ * FOURH;
    float* hso = hsout + (size_t)dir * SEQ * HID;
    float* hb_d = hbuf + dir * 2 * HID;
    unsigned* cnt = syncc + dir * 32;   // separate cache lines per direction

    const int col = tid & (WCOLS - 1);
    const int seg = tid >> 7;           // 0..7, each covers 64 k's
    const int gcol = (col >> 5) * HID + j0 + (col & 31);

    // ---- stage this thread's 64 Wh values into registers (dtype-branched, cold) ----
    float wreg[64];
    if (isf32) {
        const float* wp = (const float*)Wh + (size_t)(seg * 64) * FOURH + gcol;
#pragma unroll
        for (int kk = 0; kk < 64; ++kk) wreg[kk] = wp[(size_t)kk * FOURH];
    } else {
        const unsigned short* wp = (const unsigned short*)Wh + (size_t)(seg * 64) * FOURH + gcol;
#pragma unroll
        for (int kk = 0; kk < 64; ++kk) wreg[kk] = bf2f(wp[(size_t)kk * FOURH]);
    }

    if (tid < JPW) cb[tid] = ldf(c0, dir * HID + j0 + tid, isf32);
    // init ONLY parity 0 with h0. Each thread tid<512 writes hb_d[tid] and is also
    // the thread that reads hb_d[tid] at s=0 (same thread, same address: coherent);
    // other WGs write identical values (benign race).
    if (tid < HID)
        __hip_atomic_store(&hb_d[tid], ldf(h0, dir * HID + tid, isf32),
                           __ATOMIC_RELAXED, __HIP_MEMORY_SCOPE_AGENT);
    __syncthreads();

    // prefetch pre values for step 0
    unsigned short zpf = 0;
    if (tid < WCOLS) {
        int t0 = dir ? (SEQ - 1) : 0;
        zpf = pre_d[(size_t)t0 * FOURH + ((tid >> 5) * HID + j0 + (tid & 31))];
    }

    for (int s = 0; s < SEQ; ++s) {
        const int t = dir ? (SEQ - 1 - s) : s;

        // ---- wait for step s-1's arrivals (single spinner, relaxed loads) ----
        if (s > 0 && tid == 0) {
            const unsigned target = (unsigned)s * NWG_DIR;
            while (__hip_atomic_load(cnt, __ATOMIC_RELAXED, __HIP_MEMORY_SCOPE_AGENT) < target)
                __builtin_amdgcn_s_sleep(1);
            __builtin_amdgcn_fence(__ATOMIC_ACQUIRE, "agent");
        }
        __syncthreads();   // (B) releases all waves once tid0 has acquired

        if (tid < HID)
            hs[tid] = __hip_atomic_load(&hb_d[(s & 1) * HID + tid],
                                        __ATOMIC_RELAXED, __HIP_MEMORY_SCOPE_AGENT);
        if (tid < WCOLS)
            zb[tid] = bf2f(zpf);
        __syncthreads();   // (C)

        // prefetch next step's pre values (overlaps matvec/gates/spin)
        if (tid < WCOLS) {
            int tn = dir ? (SEQ - 2 - s) : (s + 1);
            if (s + 1 < SEQ)
                zpf = pre_d[(size_t)tn * FOURH + ((tid >> 5) * HID + j0 + (tid & 31))];
        }

        // ---- matvec: acc = sum_k hs[seg*64+k] * wreg[k] ----
        float a0 = 0.f, a1 = 0.f, a2 = 0.f, a3 = 0.f;
        const float4* hp = (const float4*)(hs + seg * 64);
#pragma unroll
        for (int q = 0; q < 4; ++q) {
#pragma unroll
            for (int r = 0; r < 4; ++r) {
                float4 h4 = hp[q * 4 + r];
                int base = (q * 4 + r) * 4;
                if (r == 0) a0 += h4.x * wreg[base] + h4.y * wreg[base + 1] + h4.z * wreg[base + 2] + h4.w * wreg[base + 3];
                if (r == 1) a1 += h4.x * wreg[base] + h4.y * wreg[base + 1] + h4.z * wreg[base + 2] + h4.w * wreg[base + 3];
                if (r == 2) a2 += h4.x * wreg[base] + h4.y * wreg[base + 1] + h4.z * wreg[base + 2] + h4.w * wreg[base + 3];
                if (r == 3) a3 += h4.x * wreg[base] + h4.y * wreg[base + 1] + h4.z * wreg[base + 2] + h4.w * wreg[base + 3];
            }
        }
        red[seg * WCOLS + col] = (a0 + a1) + (a2 + a3);
        __syncthreads();   // (D)

        if (tid < JPW) {
            int jj = tid;
            float z[4];
#pragma unroll
            for (int gt = 0; gt < 4; ++gt) {
                int c2 = gt * JPW + jj;
                float zt = zb[c2];
#pragma unroll
                for (int s8 = 0; s8 < 8; ++s8) zt += red[s8 * WCOLS + c2];
                z[gt] = satz(zt);
            }
            float cprev = cb[jj];
            float ig = sigm(z[0]);
            float fg = sigm(z[1]);
            float gg = tanhf(z[2]);
            float og = sigm(z[3]);
            float cnew = fg * cprev + ig * gg;
            cb[jj] = cnew;
            float hnew = og * tanhf(fminf(fmaxf(cnew, -60.f), 60.f));
            int jidx = j0 + jj;
            __hip_atomic_store(&hb_d[((s + 1) & 1) * HID + jidx], hnew,
                               __ATOMIC_RELAXED, __HIP_MEMORY_SCOPE_AGENT);
            hso[(size_t)t * HID + jidx] = hnew;
        }
        // ---- arrival: wave0's h-stores are program-ordered before tid0's release ----
        if (tid == 0) {
            __builtin_amdgcn_fence(__ATOMIC_RELEASE, "agent");
            __hip_atomic_fetch_add(cnt, 1u, __ATOMIC_RELAXED, __HIP_MEMORY_SCOPE_AGENT);
        }
        // non-wave0 threads proceed to (B) of next iteration and wait there.
    }
}

// ---------------------------------------------------------------- out = concat(hf,hb)@W_out + b, log_softmax (f32 out)
__global__ __launch_bounds__(64) void outproj_kernel(const float* __restrict__ hsout,
        const void* __restrict__ W_out, const void* __restrict__ b_out,
        float* __restrict__ out_scores, const int* __restrict__ dflag) {
    const int isf32 = *dflag;
    int t = blockIdx.x;
    int lane = threadIdx.x;
    const float* hf = hsout + (size_t)t * HID;
    const float* hb = hsout + (size_t)SEQ * HID + (size_t)t * HID;
    float acc[NT];
#pragma unroll
    for (int j = 0; j < NT; ++j) acc[j] = 0.f;
    for (int k = lane; k < HID; k += 64) {
        float a = hf[k], b2 = hb[k];
#pragma unroll
        for (int j = 0; j < NT; ++j)
            acc[j] += a * ldf(W_out, (size_t)k * NT + j, isf32)
                    + b2 * ldf(W_out, (size_t)(HID + k) * NT + j, isf32);
    }
#pragma unroll
    for (int off = 32; off >= 1; off >>= 1) {
#pragma unroll
        for (int j = 0; j < NT; ++j) acc[j] += __shfl_xor(acc[j], off, 64);
    }
    float o[NT];
    float m = -1e30f;
#pragma unroll
    for (int j = 0; j < NT; ++j) { o[j] = acc[j] + ldf(b_out, j, isf32); m = fmaxf(m, o[j]); }
    float lse = 0.f;
#pragma unroll
    for (int j = 0; j < NT; ++j) lse += expf(o[j] - m);
    lse = m + logf(lse);
    if (lane < NT)
        out_scores[t * NT + lane] = o[lane] - lse;
}

// ---------------------------------------------------------------- Viterbi (single wave, lanes = tags; f32 path out)
__global__ __launch_bounds__(64) void viterbi_kernel(const float* __restrict__ em,
        const void* __restrict__ trans, const void* __restrict__ strans,
        const void* __restrict__ etrans, float* __restrict__ out_path,
        const int* __restrict__ dflag) {
    __shared__ unsigned char hist[SEQ][NT];
    const int isf32 = *dflag;
    int lane = threadIdx.x;
    int j = lane < NT ? lane : 0;
    float tr[NT];
#pragma unroll
    for (int i = 0; i < NT; ++i) tr[i] = ldf(trans, i * NT + j, isf32);
    float score = ldf(strans, j, isf32) + em[j];
    for (int t = 1; t < SEQ; ++t) {
        float pe = em[t * NT + j];          // independent of the shuffle chain
        float best = -1e30f;
        int arg = 0;
#pragma unroll
        for (int i = 0; i < NT; ++i) {
            float si = __shfl(score, i, 64);
            float cand = si + tr[i];
            if (cand > best) { best = cand; arg = i; }   // strict > == first-index tie-break
        }
        if (lane < NT) hist[t][lane] = (unsigned char)arg;
        score = best + pe;
    }
    score += ldf(etrans, j, isf32);
    float bmax = -1e30f;
    int last = 0;
#pragma unroll
    for (int i = 0; i < NT; ++i) {
        float si = __shfl(score, i, 64);
        if (si > bmax) { bmax = si; last = i; }
    }
    if (lane == 0) {
        int cur = last;
        out_path[SEQ - 1] = (float)cur;
        for (int t = SEQ - 1; t >= 1; --t) {
            cur = hist[t][cur];
            out_path[t - 1] = (float)cur;
        }
    }
}

// ---------------------------------------------------------------- launch
extern "C" void kernel_launch(void* const* d_in, const int* in_sizes, int n_in,
                              void* d_out, int out_size, void* d_ws, size_t ws_size,
                              hipStream_t stream) {
    const int* x      = (const int*)d_in[0];
    const int* casing = (const int*)d_in[1];
    const int* posi   = (const int*)d_in[2];
    const void* h0    = d_in[3];
    const void* c0    = d_in[4];
    const void* W_emb = d_in[5];
    const void* W_cas = d_in[6];
    const void* W_pos = d_in[7];
    const void* Wx_f  = d_in[8];
    const void* Wh_f  = d_in[9];
    const void* b_f   = d_in[10];
    const void* Wx_b  = d_in[11];
    const void* Wh_b  = d_in[12];
    const void* b_b   = d_in[13];
    const void* W_out = d_in[14];
    const void* b_out = d_in[15];
    const void* trans = d_in[16];
    const void* strans = d_in[17];
    const void* etrans = d_in[18];

    // workspace layout (~14.3 MB total)
    char* ws = (char*)d_ws;
    unsigned* syncc     = (unsigned*)ws;                          // counters at +0,+128; flag at +448
    int* dflag          = (int*)(ws + 448);
    float* feat         = (float*)(ws + 512);                     // 1024*400 f32 = 1,638,400
    unsigned short* pre = (unsigned short*)(ws + 1638912);        // 2*1024*2048 bf16 = 8,388,608
    float* hsout        = (float*)(ws + 10027520);                // 2*1024*512 f32 = 4,194,304
    float* hbuf         = (float*)(ws + 14221824);                // 2*2*512 f32 = 8,192

    // d_out is FLOAT32: 13312 tag_scores then 1024 path values
    float* out_scores = (float*)d_out;
    float* out_path   = out_scores + SEQ * NT;

    hipMemsetAsync(syncc, 0, 512, stream);

    detect_kernel<<<1, 64, 0, stream>>>((const unsigned short*)W_emb, dflag);

    embed_kernel<<<SEQ, 128, 0, stream>>>(x, casing, posi, W_emb, W_cas, W_pos, feat, dflag);

    dim3 g2(8, 64, 2);
    pre_gemm_kernel<<<g2, 256, 0, stream>>>(feat, Wx_f, b_f, Wx_b, b_b, pre, dflag);

    lstm_kernel<<<2 * NWG_DIR, LSTM_THREADS, 0, stream>>>(
        Wh_f, Wh_b, h0, c0, pre, hsout, hbuf, syncc, dflag);

    outproj_kernel<<<SEQ, 64, 0, stream>>>(hsout, W_out, b_out, out_scores, dflag);

    viterbi_kernel<<<1, 64, 0, stream>>>(out_scores, trans, strans, etrans, out_path, dflag);
}

// Round 7
// 3514.512 us; speedup vs baseline: 3.7301x; 1.0690x over previous
//
#include <hip/hip_runtime.h>
#include <hip/hip_bf16.h>
#include <math.h>

#define SEQ 1024
#define HID 512
#define FOURH 2048
#define IND 400
#define NT 13

#define NWG_DIR 16
#define LSTM_THREADS 1024
#define JPW 32      // hidden units per WG
#define WCOLS 128   // gate columns per WG (4 gates * 32 j)

__device__ __forceinline__ float bf2f(unsigned short u) {
    union { unsigned u32; float f; } v;
    v.u32 = ((unsigned)u) << 16;
    return v.f;
}

__device__ __forceinline__ unsigned short f2bf(float f) {
    union { float f; unsigned u; } v;
    v.f = f;
    unsigned u = v.u;
    unsigned rounding = 0x7FFFu + ((u >> 16) & 1u);
    u += rounding;
    return (unsigned short)(u >> 16);
}

// dtype-agnostic float load: isf32 selects f32 vs bf16 interpretation
__device__ __forceinline__ float ldf(const void* p, size_t i, int isf32) {
    return isf32 ? ((const float*)p)[i] : bf2f(((const unsigned short*)p)[i]);
}

__device__ __forceinline__ float sigm(float x) { return 1.0f / (1.0f + expf(-x)); }
// saturating clamp: numerically identical for |z|<60 (sigm/tanh saturated beyond),
// and fminf/fmaxf squash NaN -> LSTM output provably finite.
__device__ __forceinline__ float satz(float z) { return fminf(fmaxf(z, -60.f), 60.f); }

// ---------------------------------------------------------------- input dtype detection
__global__ __launch_bounds__(64) void detect_kernel(const unsigned short* __restrict__ w,
                                                    int* __restrict__ flag) {
    int lane = threadIdx.x;
    int cnt = 0;
    for (int i = 0; i < 4; ++i) {
        unsigned short u = w[2 * (lane * 4 + i)];   // low half if buffer is f32
        int e = (u >> 7) & 0xFF;
        if (e >= 90 && e < 127) cnt++;
    }
#pragma unroll
    for (int off = 32; off >= 1; off >>= 1) cnt += __shfl_xor(cnt, off, 64);
    if (lane == 0) *flag = (cnt < 128) ? 1 : 0;    // 1 => inputs are float32
}

// ---------------------------------------------------------------- embedding
__global__ void embed_kernel(const int* __restrict__ x, const int* __restrict__ cas,
                             const int* __restrict__ pos,
                             const void* __restrict__ W_emb,
                             const void* __restrict__ W_cas,
                             const void* __restrict__ W_pos,
                             float* __restrict__ feat, const int* __restrict__ dflag) {
    const int isf32 = *dflag;
    int t = blockIdx.x;
    int xi = x[t], ci = cas[t], pi = pos[t];
    for (int e = threadIdx.x; e < IND; e += blockDim.x) {
        float v;
        if (e < 300)      v = ldf(W_emb, (size_t)xi * 300 + e, isf32);
        else if (e < 350) v = ldf(W_cas, (size_t)ci * 50 + (e - 300), isf32);
        else              v = ldf(W_pos, (size_t)pi * 50 + (e - 350), isf32);
        feat[t * IND + e] = v;
    }
}

// ---------------------------------------------------------------- pre = feat @ Wx + b (both dirs), bf16 out
__global__ __launch_bounds__(256) void pre_gemm_kernel(const float* __restrict__ feat,
        const void* __restrict__ Wx_f, const void* __restrict__ b_f,
        const void* __restrict__ Wx_b, const void* __restrict__ b_b,
        unsigned short* __restrict__ pre, const int* __restrict__ dflag) {
    __shared__ float ftile[16 * IND];
    const int isf32 = *dflag;
    int dir = blockIdx.z;
    const void* Wx = dir ? Wx_b : Wx_f;
    const void* bb = dir ? b_b : b_f;
    unsigned short* pre_d = pre + (size_t)dir * SEQ * FOURH;
    int r0 = blockIdx.y * 16;
    int col = blockIdx.x * 256 + threadIdx.x;

    for (int idx = threadIdx.x; idx < 16 * IND; idx += 256) {
        int r = idx / IND;
        int k = idx - r * IND;
        ftile[idx] = feat[(size_t)(r0 + r) * IND + k];
    }
    __syncthreads();

    float acc[16];
    float bias = ldf(bb, col, isf32);
#pragma unroll
    for (int r = 0; r < 16; ++r) acc[r] = bias;

    for (int kk = 0; kk < 100; ++kk) {
        int k = kk * 4;
        float w0 = ldf(Wx, (size_t)(k + 0) * FOURH + col, isf32);
        float w1 = ldf(Wx, (size_t)(k + 1) * FOURH + col, isf32);
        float w2 = ldf(Wx, (size_t)(k + 2) * FOURH + col, isf32);
        float w3 = ldf(Wx, (size_t)(k + 3) * FOURH + col, isf32);
#pragma unroll
        for (int r = 0; r < 16; ++r) {
            float4 f = *(const float4*)&ftile[r * IND + k];
            acc[r] += f.x * w0 + f.y * w1 + f.z * w2 + f.w * w3;
        }
    }
    for (int r = 0; r < 16; ++r) pre_d[(size_t)(r0 + r) * FOURH + col] = f2bf(acc[r]);
}

// ---------------------------------------------------------------- persistent bidirectional LSTM
// 32 WGs (16/dir), 1024 threads. Wh slice (512x128) in REGISTERS (64 f32/thread).
// Cross-WG sync: per-WG flag words (one cacheline/dir) + coalesced 16-lane poll.
// All cross-WG data moves via sc1 agent-scope atomics (per-instruction LLC
// coherent); ordering via wave-wide s_waitcnt(0) + workgroup-scope fences.
// NO agent fences -> no per-step buffer_wbl2 / buffer_inv.
__global__ __launch_bounds__(LSTM_THREADS, 4) void lstm_kernel(
        const void* __restrict__ Wh_f, const void* __restrict__ Wh_b,
        const void* __restrict__ h0, const void* __restrict__ c0,
        const unsigned short* __restrict__ pre, float* __restrict__ hsout,
        float* hbuf, unsigned* syncc, const int* __restrict__ dflag) {
    __shared__ float hs[HID];            // broadcast h for this step
    __shared__ float red[8 * WCOLS];     // per-seg partial dots
    __shared__ float zb[WCOLS];          // pre (input projection) values
    __shared__ float cb[JPW];            // cell state

    const int isf32 = *dflag;
    const int tid = threadIdx.x;
    const int b = blockIdx.x;
    const int dir = b & 1;
    const int g = b >> 1;            // 0..15
    const int j0 = g * JPW;

    const void* Wh = dir ? Wh_b : Wh_f;
    const unsigned short* pre_d = pre + (size_t)dir * SEQ * FOURH;
    float* hso = hsout + (size_t)dir * SEQ * HID;
    float* hb_d = hbuf + dir * 2 * HID;
    unsigned* flags = syncc + dir * 32;  // 16 words in one 64B line per direction

    const int col = tid & (WCOLS - 1);
    const int seg = tid >> 7;           // 0..7, each covers 64 k's
    const int gcol = (col >> 5) * HID + j0 + (col & 31);

    // ---- stage this thread's 64 Wh values into registers (dtype-branched, cold) ----
    float wreg[64];
    if (isf32) {
        const float* wp = (const float*)Wh + (size_t)(seg * 64) * FOURH + gcol;
#pragma unroll
        for (int kk = 0; kk < 64; ++kk) wreg[kk] = wp[(size_t)kk * FOURH];
    } else {
        const unsigned short* wp = (const unsigned short*)Wh + (size_t)(seg * 64) * FOURH + gcol;
#pragma unroll
        for (int kk = 0; kk < 64; ++kk) wreg[kk] = bf2f(wp[(size_t)kk * FOURH]);
    }

    if (tid < JPW) cb[tid] = ldf(c0, dir * HID + j0 + tid, isf32);
    // init ONLY parity 0 with h0 (identical values from all WGs: benign race).
    if (tid < HID)
        __hip_atomic_store(&hb_d[tid], ldf(h0, dir * HID + tid, isf32),
                           __ATOMIC_RELAXED, __HIP_MEMORY_SCOPE_AGENT);
    __syncthreads();

    // prefetch pre values for step 0
    unsigned short zpf = 0;
    if (tid < WCOLS) {
        int t0 = dir ? (SEQ - 1) : 0;
        zpf = pre_d[(size_t)t0 * FOURH + ((tid >> 5) * HID + j0 + (tid & 31))];
    }

    for (int s = 0; s < SEQ; ++s) {
        const int t = dir ? (SEQ - 1 - s) : s;

        // ---- wait for step s-1: wave 0 polls all 16 flags in one coalesced load ----
        if (s > 0) {
            if (tid < 64) {
                const unsigned tgt = (unsigned)s;
                for (;;) {
                    unsigned v = tgt;
                    if (tid < NWG_DIR)
                        v = __hip_atomic_load(&flags[tid], __ATOMIC_RELAXED,
                                              __HIP_MEMORY_SCOPE_AGENT);
                    if (__ballot(v >= tgt) == ~0ull) break;
                    __builtin_amdgcn_s_sleep(1);
                }
            }
            __builtin_amdgcn_fence(__ATOMIC_ACQUIRE, "workgroup");  // compiler order, no inv
        }
        __syncthreads();   // (B)

        if (tid < HID)
            hs[tid] = __hip_atomic_load(&hb_d[(s & 1) * HID + tid],
                                        __ATOMIC_RELAXED, __HIP_MEMORY_SCOPE_AGENT);
        if (tid < WCOLS)
            zb[tid] = bf2f(zpf);
        __syncthreads();   // (C)

        // prefetch next step's pre values (overlaps matvec/gates/spin)
        if (tid < WCOLS) {
            int tn = dir ? (SEQ - 2 - s) : (s + 1);
            if (s + 1 < SEQ)
                zpf = pre_d[(size_t)tn * FOURH + ((tid >> 5) * HID + j0 + (tid & 31))];
        }

        // ---- matvec: acc = sum_k hs[seg*64+k] * wreg[k] ----
        float a0 = 0.f, a1 = 0.f, a2 = 0.f, a3 = 0.f;
        const float4* hp = (const float4*)(hs + seg * 64);
#pragma unroll
        for (int q = 0; q < 4; ++q) {
#pragma unroll
            for (int r = 0; r < 4; ++r) {
                float4 h4 = hp[q * 4 + r];
                int base = (q * 4 + r) * 4;
                if (r == 0) a0 += h4.x * wreg[base] + h4.y * wreg[base + 1] + h4.z * wreg[base + 2] + h4.w * wreg[base + 3];
                if (r == 1) a1 += h4.x * wreg[base] + h4.y * wreg[base + 1] + h4.z * wreg[base + 2] + h4.w * wreg[base + 3];
                if (r == 2) a2 += h4.x * wreg[base] + h4.y * wreg[base + 1] + h4.z * wreg[base + 2] + h4.w * wreg[base + 3];
                if (r == 3) a3 += h4.x * wreg[base] + h4.y * wreg[base + 1] + h4.z * wreg[base + 2] + h4.w * wreg[base + 3];
            }
        }
        red[seg * WCOLS + col] = (a0 + a1) + (a2 + a3);
        __syncthreads();   // (D)

        if (tid < JPW) {
            int jj = tid;
            float z[4];
#pragma unroll
            for (int gt = 0; gt < 4; ++gt) {
                int c2 = gt * JPW + jj;
                float zt = zb[c2];
#pragma unroll
                for (int s8 = 0; s8 < 8; ++s8) zt += red[s8 * WCOLS + c2];
                z[gt] = satz(zt);
            }
            float cprev = cb[jj];
            float ig = sigm(z[0]);
            float fg = sigm(z[1]);
            float gg = tanhf(z[2]);
            float og = sigm(z[3]);
            float cnew = fg * cprev + ig * gg;
            cb[jj] = cnew;
            float hnew = og * tanhf(fminf(fmaxf(cnew, -60.f), 60.f));
            int jidx = j0 + jj;
            __hip_atomic_store(&hb_d[((s + 1) & 1) * HID + jidx], hnew,
                               __ATOMIC_RELAXED, __HIP_MEMORY_SCOPE_AGENT);
            hso[(size_t)t * HID + jidx] = hnew;
        }
        // ---- arrival: wave-wide waitcnt(0) guarantees the wave-0 h-stores are
        // ack'd at LLC (sc1 write-through) before the flag store; fence gives
        // compiler ordering. No agent fence -> no wbl2.
        __builtin_amdgcn_s_waitcnt(0);
        __builtin_amdgcn_fence(__ATOMIC_RELEASE, "workgroup");
        if (tid == 0)
            __hip_atomic_store(&flags[g], (unsigned)(s + 1),
                               __ATOMIC_RELAXED, __HIP_MEMORY_SCOPE_AGENT);
    }
}

// ---------------------------------------------------------------- out = concat(hf,hb)@W_out + b, log_softmax (f32 out)
__global__ __launch_bounds__(64) void outproj_kernel(const float* __restrict__ hsout,
        const void* __restrict__ W_out, const void* __restrict__ b_out,
        float* __restrict__ out_scores, const int* __restrict__ dflag) {
    const int isf32 = *dflag;
    int t = blockIdx.x;
    int lane = threadIdx.x;
    const float* hf = hsout + (size_t)t * HID;
    const float* hb = hsout + (size_t)SEQ * HID + (size_t)t * HID;
    float acc[NT];
#pragma unroll
    for (int j = 0; j < NT; ++j) acc[j] = 0.f;
    for (int k = lane; k < HID; k += 64) {
        float a = hf[k], b2 = hb[k];
#pragma unroll
        for (int j = 0; j < NT; ++j)
            acc[j] += a * ldf(W_out, (size_t)k * NT + j, isf32)
                    + b2 * ldf(W_out, (size_t)(HID + k) * NT + j, isf32);
    }
#pragma unroll
    for (int off = 32; off >= 1; off >>= 1) {
#pragma unroll
        for (int j = 0; j < NT; ++j) acc[j] += __shfl_xor(acc[j], off, 64);
    }
    float o[NT];
    float m = -1e30f;
#pragma unroll
    for (int j = 0; j < NT; ++j) { o[j] = acc[j] + ldf(b_out, j, isf32); m = fmaxf(m, o[j]); }
    float lse = 0.f;
#pragma unroll
    for (int j = 0; j < NT; ++j) lse += expf(o[j] - m);
    lse = m + logf(lse);
    if (lane < NT)
        out_scores[t * NT + lane] = o[lane] - lse;
}

// ---------------------------------------------------------------- Viterbi (single wave, lanes = tags; f32 path out)
__global__ __launch_bounds__(64) void viterbi_kernel(const float* __restrict__ em,
        const void* __restrict__ trans, const void* __restrict__ strans,
        const void* __restrict__ etrans, float* __restrict__ out_path,
        const int* __restrict__ dflag) {
    __shared__ unsigned char hist[SEQ][NT];
    const int isf32 = *dflag;
    int lane = threadIdx.x;
    int j = lane < NT ? lane : 0;
    float tr[NT];
#pragma unroll
    for (int i = 0; i < NT; ++i) tr[i] = ldf(trans, i * NT + j, isf32);
    float score = ldf(strans, j, isf32) + em[j];
    for (int t = 1; t < SEQ; ++t) {
        float pe = em[t * NT + j];          // independent of the shuffle chain
        float best = -1e30f;
        int arg = 0;
#pragma unroll
        for (int i = 0; i < NT; ++i) {
            float si = __shfl(score, i, 64);
            float cand = si + tr[i];
            if (cand > best) { best = cand; arg = i; }   // strict > == first-index tie-break
        }
        if (lane < NT) hist[t][lane] = (unsigned char)arg;
        score = best + pe;
    }
    score += ldf(etrans, j, isf32);
    float bmax = -1e30f;
    int last = 0;
#pragma unroll
    for (int i = 0; i < NT; ++i) {
        float si = __shfl(score, i, 64);
        if (si > bmax) { bmax = si; last = i; }
    }
    if (lane == 0) {
        int cur = last;
        out_path[SEQ - 1] = (float)cur;
        for (int t = SEQ - 1; t >= 1; --t) {
            cur = hist[t][cur];
            out_path[t - 1] = (float)cur;
        }
    }
}

// ---------------------------------------------------------------- launch
extern "C" void kernel_launch(void* const* d_in, const int* in_sizes, int n_in,
                              void* d_out, int out_size, void* d_ws, size_t ws_size,
                              hipStream_t stream) {
    const int* x      = (const int*)d_in[0];
    const int* casing = (const int*)d_in[1];
    const int* posi   = (const int*)d_in[2];
    const void* h0    = d_in[3];
    const void* c0    = d_in[4];
    const void* W_emb = d_in[5];
    const void* W_cas = d_in[6];
    const void* W_pos = d_in[7];
    const void* Wx_f  = d_in[8];
    const void* Wh_f  = d_in[9];
    const void* b_f   = d_in[10];
    const void* Wx_b  = d_in[11];
    const void* Wh_b  = d_in[12];
    const void* b_b   = d_in[13];
    const void* W_out = d_in[14];
    const void* b_out = d_in[15];
    const void* trans = d_in[16];
    const void* strans = d_in[17];
    const void* etrans = d_in[18];

    // workspace layout (~14.3 MB total)
    char* ws = (char*)d_ws;
    unsigned* syncc     = (unsigned*)ws;                          // flags dir0 at +0, dir1 at +128; dflag at +448
    int* dflag          = (int*)(ws + 448);
    float* feat         = (float*)(ws + 512);                     // 1024*400 f32 = 1,638,400
    unsigned short* pre = (unsigned short*)(ws + 1638912);        // 2*1024*2048 bf16 = 8,388,608
    float* hsout        = (float*)(ws + 10027520);                // 2*1024*512 f32 = 4,194,304
    float* hbuf         = (float*)(ws + 14221824);                // 2*2*512 f32 = 8,192

    // d_out is FLOAT32: 13312 tag_scores then 1024 path values
    float* out_scores = (float*)d_out;
    float* out_path   = out_scores + SEQ * NT;

    hipMemsetAsync(syncc, 0, 512, stream);

    detect_kernel<<<1, 64, 0, stream>>>((const unsigned short*)W_emb, dflag);

    embed_kernel<<<SEQ, 128, 0, stream>>>(x, casing, posi, W_emb, W_cas, W_pos, feat, dflag);

    dim3 g2(8, 64, 2);
    pre_gemm_kernel<<<g2, 256, 0, stream>>>(feat, Wx_f, b_f, Wx_b, b_b, pre, dflag);

    lstm_kernel<<<2 * NWG_DIR, LSTM_THREADS, 0, stream>>>(
        Wh_f, Wh_b, h0, c0, pre, hsout, hbuf, syncc, dflag);

    outproj_kernel<<<SEQ, 64, 0, stream>>>(hsout, W_out, b_out, out_scores, dflag);

    viterbi_kernel<<<1, 64, 0, stream>>>(out_scores, trans, strans, etrans, out_path, dflag);
}

// Round 8
// 2779.879 us; speedup vs baseline: 4.7158x; 1.2643x over previous
//
#include <hip/hip_runtime.h>
#include <hip/hip_bf16.h>
#include <math.h>

#define SEQ 1024
#define HID 512
#define FOURH 2048
#define IND 400
#define NT 13

#define NWG_DIR 16
#define LSTM_THREADS 1024
#define JPW 32      // hidden units per WG
#define WCOLS 128   // gate columns per WG (4 gates * 32 j)
#define TAG_INVALID 0xFFFFFFFFu

__device__ __forceinline__ float bf2f(unsigned short u) {
    union { unsigned u32; float f; } v;
    v.u32 = ((unsigned)u) << 16;
    return v.f;
}

__device__ __forceinline__ unsigned short f2bf(float f) {
    union { float f; unsigned u; } v;
    v.f = f;
    unsigned u = v.u;
    unsigned rounding = 0x7FFFu + ((u >> 16) & 1u);
    u += rounding;
    return (unsigned short)(u >> 16);
}

// dtype-agnostic float load: isf32 selects f32 vs bf16 interpretation
__device__ __forceinline__ float ldf(const void* p, size_t i, int isf32) {
    return isf32 ? ((const float*)p)[i] : bf2f(((const unsigned short*)p)[i]);
}

__device__ __forceinline__ float sigm(float x) { return 1.0f / (1.0f + expf(-x)); }
// saturating clamp: numerically identical for |z|<60 (sigm/tanh saturated beyond),
// and fminf/fmaxf squash NaN -> LSTM output provably finite.
__device__ __forceinline__ float satz(float z) { return fminf(fmaxf(z, -60.f), 60.f); }

// ---------------------------------------------------------------- input dtype detection
__global__ __launch_bounds__(64) void detect_kernel(const unsigned short* __restrict__ w,
                                                    int* __restrict__ flag) {
    int lane = threadIdx.x;
    int cnt = 0;
    for (int i = 0; i < 4; ++i) {
        unsigned short u = w[2 * (lane * 4 + i)];   // low half if buffer is f32
        int e = (u >> 7) & 0xFF;
        if (e >= 90 && e < 127) cnt++;
    }
#pragma unroll
    for (int off = 32; off >= 1; off >>= 1) cnt += __shfl_xor(cnt, off, 64);
    if (lane == 0) *flag = (cnt < 128) ? 1 : 0;    // 1 => inputs are float32
}

// ---------------------------------------------------------------- embedding
__global__ void embed_kernel(const int* __restrict__ x, const int* __restrict__ cas,
                             const int* __restrict__ pos,
                             const void* __restrict__ W_emb,
                             const void* __restrict__ W_cas,
                             const void* __restrict__ W_pos,
                             float* __restrict__ feat, const int* __restrict__ dflag) {
    const int isf32 = *dflag;
    int t = blockIdx.x;
    int xi = x[t], ci = cas[t], pi = pos[t];
    for (int e = threadIdx.x; e < IND; e += blockDim.x) {
        float v;
        if (e < 300)      v = ldf(W_emb, (size_t)xi * 300 + e, isf32);
        else if (e < 350) v = ldf(W_cas, (size_t)ci * 50 + (e - 300), isf32);
        else              v = ldf(W_pos, (size_t)pi * 50 + (e - 350), isf32);
        feat[t * IND + e] = v;
    }
}

// ---------------------------------------------------------------- pre = feat @ Wx + b (both dirs), bf16 out
__global__ __launch_bounds__(256) void pre_gemm_kernel(const float* __restrict__ feat,
        const void* __restrict__ Wx_f, const void* __restrict__ b_f,
        const void* __restrict__ Wx_b, const void* __restrict__ b_b,
        unsigned short* __restrict__ pre, const int* __restrict__ dflag) {
    __shared__ float ftile[16 * IND];
    const int isf32 = *dflag;
    int dir = blockIdx.z;
    const void* Wx = dir ? Wx_b : Wx_f;
    const void* bb = dir ? b_b : b_f;
    unsigned short* pre_d = pre + (size_t)dir * SEQ * FOURH;
    int r0 = blockIdx.y * 16;
    int col = blockIdx.x * 256 + threadIdx.x;

    for (int idx = threadIdx.x; idx < 16 * IND; idx += 256) {
        int r = idx / IND;
        int k = idx - r * IND;
        ftile[idx] = feat[(size_t)(r0 + r) * IND + k];
    }
    __syncthreads();

    float acc[16];
    float bias = ldf(bb, col, isf32);
#pragma unroll
    for (int r = 0; r < 16; ++r) acc[r] = bias;

    if (isf32) {   // hoisted dtype branch: typed inner loops
        const float* W = (const float*)Wx;
        for (int kk = 0; kk < 100; ++kk) {
            int k = kk * 4;
            float w0 = W[(size_t)(k + 0) * FOURH + col];
            float w1 = W[(size_t)(k + 1) * FOURH + col];
            float w2 = W[(size_t)(k + 2) * FOURH + col];
            float w3 = W[(size_t)(k + 3) * FOURH + col];
#pragma unroll
            for (int r = 0; r < 16; ++r) {
                float4 f = *(const float4*)&ftile[r * IND + k];
                acc[r] += f.x * w0 + f.y * w1 + f.z * w2 + f.w * w3;
            }
        }
    } else {
        const unsigned short* W = (const unsigned short*)Wx;
        for (int kk = 0; kk < 100; ++kk) {
            int k = kk * 4;
            float w0 = bf2f(W[(size_t)(k + 0) * FOURH + col]);
            float w1 = bf2f(W[(size_t)(k + 1) * FOURH + col]);
            float w2 = bf2f(W[(size_t)(k + 2) * FOURH + col]);
            float w3 = bf2f(W[(size_t)(k + 3) * FOURH + col]);
#pragma unroll
            for (int r = 0; r < 16; ++r) {
                float4 f = *(const float4*)&ftile[r * IND + k];
                acc[r] += f.x * w0 + f.y * w1 + f.z * w2 + f.w * w3;
            }
        }
    }
    for (int r = 0; r < 16; ++r) pre_d[(size_t)(r0 + r) * FOURH + col] = f2bf(acc[r]);
}

// ---------------------------------------------------------------- persistent bidirectional LSTM
// 32 WGs (16/dir), 1024 threads. Wh slice (512x128) in REGISTERS (64 f32/thread).
// Cross-WG sync: TAGGED h-words. Each h value travels as one 8-byte atomic store
// {f32 value | u32 step tag}; consumers spin on their own word until tag==s.
// The per-word tag-spin IS the barrier (one LLC round trip; no fences/flags/acks).
__global__ __launch_bounds__(LSTM_THREADS, 4) void lstm_kernel(
        const void* __restrict__ Wh_f, const void* __restrict__ Wh_b,
        const void* __restrict__ h0, const void* __restrict__ c0,
        const unsigned short* __restrict__ pre, float* __restrict__ hsout,
        unsigned long long* hbuf, const int* __restrict__ dflag) {
    __shared__ float hs[HID];            // broadcast h for this step
    __shared__ float red[8 * WCOLS];     // per-seg partial dots
    __shared__ float zb[WCOLS];          // pre (input projection) values
    __shared__ float cb[JPW];            // cell state

    const int isf32 = *dflag;
    const int tid = threadIdx.x;
    const int b = blockIdx.x;
    const int dir = b & 1;
    const int g = b >> 1;            // 0..15
    const int j0 = g * JPW;

    const void* Wh = dir ? Wh_b : Wh_f;
    const unsigned short* pre_d = pre + (size_t)dir * SEQ * FOURH;
    float* hso = hsout + (size_t)dir * SEQ * HID;
    unsigned long long* hb_d = hbuf + dir * 2 * HID;   // [parity][512] tagged words

    const int col = tid & (WCOLS - 1);
    const int seg = tid >> 7;           // 0..7, each covers 64 k's
    const int gcol = (col >> 5) * HID + j0 + (col & 31);

    // ---- stage this thread's 64 Wh values into registers (dtype-branched, cold) ----
    float wreg[64];
    if (isf32) {
        const float* wp = (const float*)Wh + (size_t)(seg * 64) * FOURH + gcol;
#pragma unroll
        for (int kk = 0; kk < 64; ++kk) wreg[kk] = wp[(size_t)kk * FOURH];
    } else {
        const unsigned short* wp = (const unsigned short*)Wh + (size_t)(seg * 64) * FOURH + gcol;
#pragma unroll
        for (int kk = 0; kk < 64; ++kk) wreg[kk] = bf2f(wp[(size_t)kk * FOURH]);
    }

    if (tid < JPW) {
        cb[tid] = ldf(c0, dir * HID + j0 + tid, isf32);
        // init ONLY own slice (no cross-WG race): parity0 = h0 tagged 0,
        // parity1 = INVALID. Same threads later produce into these slots;
        // same-address program order keeps init before produce.
        int j = j0 + tid;
        float h0v = ldf(h0, dir * HID + j, isf32);
        unsigned long long w0 = ((unsigned long long)0u << 32) | (unsigned long long)__float_as_uint(h0v);
        __hip_atomic_store(&hb_d[j], w0, __ATOMIC_RELAXED, __HIP_MEMORY_SCOPE_AGENT);
        __hip_atomic_store(&hb_d[HID + j],
                           ((unsigned long long)TAG_INVALID << 32),
                           __ATOMIC_RELAXED, __HIP_MEMORY_SCOPE_AGENT);
    }
    __syncthreads();

    // prefetch pre values for step 0
    unsigned short zpf = 0;
    if (tid < WCOLS) {
        int t0 = dir ? (SEQ - 1) : 0;
        zpf = pre_d[(size_t)t0 * FOURH + ((tid >> 5) * HID + j0 + (tid & 31))];
    }

    for (int s = 0; s < SEQ; ++s) {
        const int t = dir ? (SEQ - 1 - s) : s;

        // ---- spin on own tagged word: tag==s validates value (data IS the flag) ----
        if (tid < HID) {
            const unsigned long long* wp = &hb_d[(s & 1) * HID + tid];
            const unsigned expect = (unsigned)s;
            unsigned long long w;
            do {
                w = __hip_atomic_load(wp, __ATOMIC_RELAXED, __HIP_MEMORY_SCOPE_AGENT);
            } while ((unsigned)(w >> 32) != expect);
            hs[tid] = __uint_as_float((unsigned)w);
        }
        // zb write AFTER spin: spin success implies wave0 (this WG) produced h_{s},
        // wait no - implies ALL producers of h_s done, in particular own wave0 has
        // finished reading zb for step s-1 (produce is after its zb reads).
        if (tid < WCOLS)
            zb[tid] = bf2f(zpf);
        __syncthreads();   // (C)

        // prefetch next step's pre values (overlaps matvec/gates)
        if (tid < WCOLS) {
            int tn = dir ? (SEQ - 2 - s) : (s + 1);
            if (s + 1 < SEQ)
                zpf = pre_d[(size_t)tn * FOURH + ((tid >> 5) * HID + j0 + (tid & 31))];
        }

        // ---- matvec: acc = sum_k hs[seg*64+k] * wreg[k] ----
        float a0 = 0.f, a1 = 0.f, a2 = 0.f, a3 = 0.f;
        const float4* hp = (const float4*)(hs + seg * 64);
#pragma unroll
        for (int q = 0; q < 4; ++q) {
#pragma unroll
            for (int r = 0; r < 4; ++r) {
                float4 h4 = hp[q * 4 + r];
                int base = (q * 4 + r) * 4;
                if (r == 0) a0 += h4.x * wreg[base] + h4.y * wreg[base + 1] + h4.z * wreg[base + 2] + h4.w * wreg[base + 3];
                if (r == 1) a1 += h4.x * wreg[base] + h4.y * wreg[base + 1] + h4.z * wreg[base + 2] + h4.w * wreg[base + 3];
                if (r == 2) a2 += h4.x * wreg[base] + h4.y * wreg[base + 1] + h4.z * wreg[base + 2] + h4.w * wreg[base + 3];
                if (r == 3) a3 += h4.x * wreg[base] + h4.y * wreg[base + 1] + h4.z * wreg[base + 2] + h4.w * wreg[base + 3];
            }
        }
        red[seg * WCOLS + col] = (a0 + a1) + (a2 + a3);
        __syncthreads();   // (D)

        if (tid < JPW) {
            int jj = tid;
            float z[4];
#pragma unroll
            for (int gt = 0; gt < 4; ++gt) {
                int c2 = gt * JPW + jj;
                float zt = zb[c2];
#pragma unroll
                for (int s8 = 0; s8 < 8; ++s8) zt += red[s8 * WCOLS + c2];
                z[gt] = satz(zt);
            }
            float cprev = cb[jj];
            float ig = sigm(z[0]);
            float fg = sigm(z[1]);
            float gg = tanhf(z[2]);
            float og = sigm(z[3]);
            float cnew = fg * cprev + ig * gg;
            cb[jj] = cnew;
            float hnew = og * tanhf(fminf(fmaxf(cnew, -60.f), 60.f));
            int jidx = j0 + jj;
            // critical-path store FIRST: tagged word (single 8B atomic store)
            unsigned long long w = ((unsigned long long)(unsigned)(s + 1) << 32)
                                 | (unsigned long long)__float_as_uint(hnew);
            __hip_atomic_store(&hb_d[((s + 1) & 1) * HID + jidx], w,
                               __ATOMIC_RELAXED, __HIP_MEMORY_SCOPE_AGENT);
            hso[(size_t)t * HID + jidx] = hnew;
        }
        // no trailing barrier: next iteration's tag-spin is the sync
    }
}

// ---------------------------------------------------------------- out = concat(hf,hb)@W_out + b, log_softmax (f32 out)
__global__ __launch_bounds__(64) void outproj_kernel(const float* __restrict__ hsout,
        const void* __restrict__ W_out, const void* __restrict__ b_out,
        float* __restrict__ out_scores, const int* __restrict__ dflag) {
    const int isf32 = *dflag;
    int t = blockIdx.x;
    int lane = threadIdx.x;
    const float* hf = hsout + (size_t)t * HID;
    const float* hb = hsout + (size_t)SEQ * HID + (size_t)t * HID;
    float acc[NT];
#pragma unroll
    for (int j = 0; j < NT; ++j) acc[j] = 0.f;
    for (int k = lane; k < HID; k += 64) {
        float a = hf[k], b2 = hb[k];
#pragma unroll
        for (int j = 0; j < NT; ++j)
            acc[j] += a * ldf(W_out, (size_t)k * NT + j, isf32)
                    + b2 * ldf(W_out, (size_t)(HID + k) * NT + j, isf32);
    }
#pragma unroll
    for (int off = 32; off >= 1; off >>= 1) {
#pragma unroll
        for (int j = 0; j < NT; ++j) acc[j] += __shfl_xor(acc[j], off, 64);
    }
    float o[NT];
    float m = -1e30f;
#pragma unroll
    for (int j = 0; j < NT; ++j) { o[j] = acc[j] + ldf(b_out, j, isf32); m = fmaxf(m, o[j]); }
    float lse = 0.f;
#pragma unroll
    for (int j = 0; j < NT; ++j) lse += expf(o[j] - m);
    lse = m + logf(lse);
    if (lane < NT)
        out_scores[t * NT + lane] = o[lane] - lse;
}

// ---------------------------------------------------------------- Viterbi (single wave, lanes = tags; f32 path out)
__global__ __launch_bounds__(64) void viterbi_kernel(const float* __restrict__ em,
        const void* __restrict__ trans, const void* __restrict__ strans,
        const void* __restrict__ etrans, float* __restrict__ out_path,
        const int* __restrict__ dflag) {
    __shared__ unsigned char hist[SEQ][NT];
    const int isf32 = *dflag;
    int lane = threadIdx.x;
    int j = lane < NT ? lane : 0;
    float tr[NT];
#pragma unroll
    for (int i = 0; i < NT; ++i) tr[i] = ldf(trans, i * NT + j, isf32);
    float score = ldf(strans, j, isf32) + em[j];
    for (int t = 1; t < SEQ; ++t) {
        float pe = em[t * NT + j];          // independent of the shuffle chain
        float best = -1e30f;
        int arg = 0;
#pragma unroll
        for (int i = 0; i < NT; ++i) {
            float si = __shfl(score, i, 64);
            float cand = si + tr[i];
            if (cand > best) { best = cand; arg = i; }   // strict > == first-index tie-break
        }
        if (lane < NT) hist[t][lane] = (unsigned char)arg;
        score = best + pe;
    }
    score += ldf(etrans, j, isf32);
    float bmax = -1e30f;
    int last = 0;
#pragma unroll
    for (int i = 0; i < NT; ++i) {
        float si = __shfl(score, i, 64);
        if (si > bmax) { bmax = si; last = i; }
    }
    if (lane == 0) {
        int cur = last;
        out_path[SEQ - 1] = (float)cur;
        for (int t = SEQ - 1; t >= 1; --t) {
            cur = hist[t][cur];
            out_path[t - 1] = (float)cur;
        }
    }
}

// ---------------------------------------------------------------- launch
extern "C" void kernel_launch(void* const* d_in, const int* in_sizes, int n_in,
                              void* d_out, int out_size, void* d_ws, size_t ws_size,
                              hipStream_t stream) {
    const int* x      = (const int*)d_in[0];
    const int* casing = (const int*)d_in[1];
    const int* posi   = (const int*)d_in[2];
    const void* h0    = d_in[3];
    const void* c0    = d_in[4];
    const void* W_emb = d_in[5];
    const void* W_cas = d_in[6];
    const void* W_pos = d_in[7];
    const void* Wx_f  = d_in[8];
    const void* Wh_f  = d_in[9];
    const void* b_f   = d_in[10];
    const void* Wx_b  = d_in[11];
    const void* Wh_b  = d_in[12];
    const void* b_b   = d_in[13];
    const void* W_out = d_in[14];
    const void* b_out = d_in[15];
    const void* trans = d_in[16];
    const void* strans = d_in[17];
    const void* etrans = d_in[18];

    // workspace layout (~14.3 MB total)
    char* ws = (char*)d_ws;
    int* dflag          = (int*)(ws + 448);
    float* feat         = (float*)(ws + 512);                     // 1024*400 f32 = 1,638,400
    unsigned short* pre = (unsigned short*)(ws + 1638912);        // 2*1024*2048 bf16 = 8,388,608
    float* hsout        = (float*)(ws + 10027520);                // 2*1024*512 f32 = 4,194,304
    unsigned long long* hbuf = (unsigned long long*)(ws + 14221824); // 2*2*512 u64 = 16,384 (tagged h words)

    // d_out is FLOAT32: 13312 tag_scores then 1024 path values
    float* out_scores = (float*)d_out;
    float* out_path   = out_scores + SEQ * NT;

    detect_kernel<<<1, 64, 0, stream>>>((const unsigned short*)W_emb, dflag);

    embed_kernel<<<SEQ, 128, 0, stream>>>(x, casing, posi, W_emb, W_cas, W_pos, feat, dflag);

    dim3 g2(8, 64, 2);
    pre_gemm_kernel<<<g2, 256, 0, stream>>>(feat, Wx_f, b_f, Wx_b, b_b, pre, dflag);

    lstm_kernel<<<2 * NWG_DIR, LSTM_THREADS, 0, stream>>>(
        Wh_f, Wh_b, h0, c0, pre, hsout, hbuf, dflag);

    outproj_kernel<<<SEQ, 64, 0, stream>>>(hsout, W_out, b_out, out_scores, dflag);

    viterbi_kernel<<<1, 64, 0, stream>>>(out_scores, trans, strans, etrans, out_path, dflag);
}

// Round 9
// 2519.652 us; speedup vs baseline: 5.2029x; 1.1033x over previous
//
#include <hip/hip_runtime.h>
#include <hip/hip_bf16.h>
#include <math.h>

#define SEQ 1024
#define HID 512
#define FOURH 2048
#define IND 400
#define NT 13

#define NWG_DIR 32
#define LSTM_THREADS 512
#define JPW 16      // hidden units per WG
#define WCOLS 64    // gate columns per WG (4 gates * 16 units)
#define TAG_INVALID 0xFFFFFFFFu

__device__ __forceinline__ float bf2f(unsigned short u) {
    union { unsigned u32; float f; } v;
    v.u32 = ((unsigned)u) << 16;
    return v.f;
}

__device__ __forceinline__ unsigned short f2bf(float f) {
    union { float f; unsigned u; } v;
    v.f = f;
    unsigned u = v.u;
    unsigned rounding = 0x7FFFu + ((u >> 16) & 1u);
    u += rounding;
    return (unsigned short)(u >> 16);
}

// dtype-agnostic float load: isf32 selects f32 vs bf16 interpretation
__device__ __forceinline__ float ldf(const void* p, size_t i, int isf32) {
    return isf32 ? ((const float*)p)[i] : bf2f(((const unsigned short*)p)[i]);
}

// fast transcendentals: v_exp_f32 / v_rcp_f32 based; abs err ~1e-7
__device__ __forceinline__ float fsigm(float x) {
    return __builtin_amdgcn_rcpf(1.f + __builtin_amdgcn_exp2f(-1.44269504f * x));
}
__device__ __forceinline__ float ftanhf(float x) {
    return 1.f - 2.f * __builtin_amdgcn_rcpf(__builtin_amdgcn_exp2f(2.88539008f * x) + 1.f);
}
// saturating clamp (also squashes NaN from any garbage input)
__device__ __forceinline__ float satz(float z) { return fminf(fmaxf(z, -60.f), 60.f); }

// ---------------------------------------------------------------- input dtype detection + counter zero
__global__ __launch_bounds__(64) void detect_kernel(const unsigned short* __restrict__ w,
                                                    int* __restrict__ flag,
                                                    unsigned* __restrict__ vcnt) {
    int lane = threadIdx.x;
    int cnt = 0;
    for (int i = 0; i < 4; ++i) {
        unsigned short u = w[2 * (lane * 4 + i)];   // low half if buffer is f32
        int e = (u >> 7) & 0xFF;
        if (e >= 90 && e < 127) cnt++;
    }
#pragma unroll
    for (int off = 32; off >= 1; off >>= 1) cnt += __shfl_xor(cnt, off, 64);
    if (lane == 0) *flag = (cnt < 128) ? 1 : 0;    // 1 => inputs are float32
    if (lane == 1) *vcnt = 0;                      // outproj->viterbi completion counter
}

// ---------------------------------------------------------------- pre = feat @ Wx + b (embed fused, both dirs), bf16 out
__global__ __launch_bounds__(256) void pre_gemm_kernel(
        const int* __restrict__ x, const int* __restrict__ cas, const int* __restrict__ pos,
        const void* __restrict__ W_emb, const void* __restrict__ W_cas, const void* __restrict__ W_pos,
        const void* __restrict__ Wx_f, const void* __restrict__ b_f,
        const void* __restrict__ Wx_b, const void* __restrict__ b_b,
        unsigned short* __restrict__ pre, const int* __restrict__ dflag) {
    __shared__ float ftile[32 * IND];    // 51.2 KB
    __shared__ int idxs[96];
    const int isf32 = *dflag;
    int dir = blockIdx.z;
    const void* Wx = dir ? Wx_b : Wx_f;
    const void* bb = dir ? b_b : b_f;
    unsigned short* pre_d = pre + (size_t)dir * SEQ * FOURH;
    int r0 = blockIdx.y * 32;
    int col = blockIdx.x * 256 + threadIdx.x;
    int tid = threadIdx.x;

    if (tid < 32)       idxs[tid] = x[r0 + tid];
    else if (tid < 64)  idxs[tid] = cas[r0 + tid - 32];
    else if (tid < 96)  idxs[tid] = pos[r0 + tid - 64];
    __syncthreads();

    for (int idx = tid; idx < 32 * IND; idx += 256) {
        int r = idx / IND;
        int e = idx - r * IND;
        float v;
        if (e < 300)      v = ldf(W_emb, (size_t)idxs[r] * 300 + e, isf32);
        else if (e < 350) v = ldf(W_cas, (size_t)idxs[32 + r] * 50 + (e - 300), isf32);
        else              v = ldf(W_pos, (size_t)idxs[64 + r] * 50 + (e - 350), isf32);
        ftile[idx] = v;
    }
    __syncthreads();

    float acc[32];
    float bias = ldf(bb, col, isf32);
#pragma unroll
    for (int r = 0; r < 32; ++r) acc[r] = bias;

    if (isf32) {
        const float* W = (const float*)Wx;
        for (int kk = 0; kk < 100; ++kk) {
            int k = kk * 4;
            float w0 = W[(size_t)(k + 0) * FOURH + col];
            float w1 = W[(size_t)(k + 1) * FOURH + col];
            float w2 = W[(size_t)(k + 2) * FOURH + col];
            float w3 = W[(size_t)(k + 3) * FOURH + col];
#pragma unroll
            for (int r = 0; r < 32; ++r) {
                float4 f = *(const float4*)&ftile[r * IND + k];
                acc[r] += f.x * w0 + f.y * w1 + f.z * w2 + f.w * w3;
            }
        }
    } else {
        const unsigned short* W = (const unsigned short*)Wx;
        for (int kk = 0; kk < 100; ++kk) {
            int k = kk * 4;
            float w0 = bf2f(W[(size_t)(k + 0) * FOURH + col]);
            float w1 = bf2f(W[(size_t)(k + 1) * FOURH + col]);
            float w2 = bf2f(W[(size_t)(k + 2) * FOURH + col]);
            float w3 = bf2f(W[(size_t)(k + 3) * FOURH + col]);
#pragma unroll
            for (int r = 0; r < 32; ++r) {
                float4 f = *(const float4*)&ftile[r * IND + k];
                acc[r] += f.x * w0 + f.y * w1 + f.z * w2 + f.w * w3;
            }
        }
    }
    for (int r = 0; r < 32; ++r) pre_d[(size_t)(r0 + r) * FOURH + col] = f2bf(acc[r]);
}

// ---------------------------------------------------------------- persistent bidirectional LSTM
// 64 WGs (32/dir) x 512 threads. Per WG: 64 gate-cols, Wh slice 512x64 in REGISTERS.
// Tagged-word h exchange: {f32 value | u32 step tag} in one 8B agent atomic store;
// consumers spin until tag==s (the spin IS the barrier; proof in r8 notes).
__global__ __launch_bounds__(LSTM_THREADS, 2) void lstm_kernel(
        const void* __restrict__ Wh_f, const void* __restrict__ Wh_b,
        const void* __restrict__ h0, const void* __restrict__ c0,
        const unsigned short* __restrict__ pre, float* __restrict__ hsout,
        unsigned long long* hbuf, const int* __restrict__ dflag) {
    __shared__ float hs[HID];            // broadcast h for this step (2 KB)
    __shared__ float red[8 * WCOLS];     // [seg][unit][gate] partial dots (2 KB)

    const int isf32 = *dflag;
    const int tid = threadIdx.x;
    const int b = blockIdx.x;
    const int dir = b & 1;
    const int g = b >> 1;            // 0..31
    const int j0 = g * JPW;          // 16-unit slice

    const void* Wh = dir ? Wh_b : Wh_f;
    const unsigned short* pre_d = pre + (size_t)dir * SEQ * FOURH;
    float* hso = hsout + (size_t)dir * SEQ * HID;
    unsigned long long* hb_d = hbuf + dir * 2 * HID;   // [parity][512] tagged words

    const int seg  = tid >> 6;          // 0..7, k-range seg*64..+63 (wave == seg)
    const int col  = tid & 63;          // 0..63
    const int unit = col & 15;
    const int gate = col >> 4;
    const int gcol = gate * HID + j0 + unit;
    const int redoff = seg * WCOLS + unit * 4 + gate;

    // ---- stage this thread's 64 Wh values into registers (cold) ----
    float wreg[64];
    if (isf32) {
        const float* wp = (const float*)Wh + (size_t)(seg * 64) * FOURH + gcol;
#pragma unroll
        for (int kk = 0; kk < 64; ++kk) wreg[kk] = wp[(size_t)kk * FOURH];
    } else {
        const unsigned short* wp = (const unsigned short*)Wh + (size_t)(seg * 64) * FOURH + gcol;
#pragma unroll
        for (int kk = 0; kk < 64; ++kk) wreg[kk] = bf2f(wp[(size_t)kk * FOURH]);
    }

    float creg = 0.f;
    unsigned short zn0 = 0, zn1 = 0, zn2 = 0, zn3 = 0;   // prefetched pre (bf16)
    if (tid < JPW) {
        creg = ldf(c0, dir * HID + j0 + tid, isf32);
        // init own slice: parity0 = h0 tagged 0, parity1 = INVALID (same-thread
        // same-address program order protects init vs later produce)
        float h0v = ldf(h0, dir * HID + j0 + tid, isf32);
        __hip_atomic_store(&hb_d[j0 + tid],
                           (unsigned long long)__float_as_uint(h0v),
                           __ATOMIC_RELAXED, __HIP_MEMORY_SCOPE_AGENT);
        __hip_atomic_store(&hb_d[HID + j0 + tid],
                           ((unsigned long long)TAG_INVALID << 32),
                           __ATOMIC_RELAXED, __HIP_MEMORY_SCOPE_AGENT);
        int t0 = dir ? (SEQ - 1) : 0;
        zn0 = pre_d[(size_t)t0 * FOURH + 0 * HID + j0 + tid];
        zn1 = pre_d[(size_t)t0 * FOURH + 1 * HID + j0 + tid];
        zn2 = pre_d[(size_t)t0 * FOURH + 2 * HID + j0 + tid];
        zn3 = pre_d[(size_t)t0 * FOURH + 3 * HID + j0 + tid];
    }
    __syncthreads();   // drains vmcnt: own tagged words at LLC before anyone spins

    for (int s = 0; s < SEQ; ++s) {
        const int t = dir ? (SEQ - 1 - s) : s;

        // ---- spin on own tagged word (all 512 threads; data IS the flag) ----
        {
            const unsigned long long* wp = &hb_d[(s & 1) * HID + tid];
            const unsigned expect = (unsigned)s;
            unsigned long long w;
            do {
                w = __hip_atomic_load(wp, __ATOMIC_RELAXED, __HIP_MEMORY_SCOPE_AGENT);
            } while ((unsigned)(w >> 32) != expect);
            hs[tid] = __uint_as_float((unsigned)w);
        }

        // producer lanes: consume prefetched pre, issue next prefetch
        float zc0 = 0.f, zc1 = 0.f, zc2 = 0.f, zc3 = 0.f;
        if (tid < JPW) {
            zc0 = bf2f(zn0); zc1 = bf2f(zn1); zc2 = bf2f(zn2); zc3 = bf2f(zn3);
            if (s + 1 < SEQ) {
                int tn = dir ? (SEQ - 2 - s) : (s + 1);
                zn0 = pre_d[(size_t)tn * FOURH + 0 * HID + j0 + tid];
                zn1 = pre_d[(size_t)tn * FOURH + 1 * HID + j0 + tid];
                zn2 = pre_d[(size_t)tn * FOURH + 2 * HID + j0 + tid];
                zn3 = pre_d[(size_t)tn * FOURH + 3 * HID + j0 + tid];
            }
        }
        __syncthreads();   // (C) hs complete

        // ---- matvec: acc = sum_k hs[seg*64+k] * wreg[k] (broadcast LDS reads) ----
        float a0 = 0.f, a1 = 0.f, a2 = 0.f, a3 = 0.f;
        const float4* hp = (const float4*)(hs + seg * 64);
#pragma unroll
        for (int q = 0; q < 16; ++q) {
            float4 h4 = hp[q];
            int base = q * 4;
            if ((q & 3) == 0) a0 += h4.x * wreg[base] + h4.y * wreg[base + 1] + h4.z * wreg[base + 2] + h4.w * wreg[base + 3];
            if ((q & 3) == 1) a1 += h4.x * wreg[base] + h4.y * wreg[base + 1] + h4.z * wreg[base + 2] + h4.w * wreg[base + 3];
            if ((q & 3) == 2) a2 += h4.x * wreg[base] + h4.y * wreg[base + 1] + h4.z * wreg[base + 2] + h4.w * wreg[base + 3];
            if ((q & 3) == 3) a3 += h4.x * wreg[base] + h4.y * wreg[base + 1] + h4.z * wreg[base + 2] + h4.w * wreg[base + 3];
        }
        red[redoff] = (a0 + a1) + (a2 + a3);
        __syncthreads();   // (D)

        // ---- gates + state update + tagged store (one quarter-wave) ----
        if (tid < JPW) {
            int jj = tid;
            float z0 = zc0, z1 = zc1, z2 = zc2, z3 = zc3;
#pragma unroll
            for (int s8 = 0; s8 < 8; ++s8) {
                float4 r4 = *(const float4*)&red[s8 * WCOLS + jj * 4];
                z0 += r4.x; z1 += r4.y; z2 += r4.z; z3 += r4.w;
            }
            z0 = satz(z0); z1 = satz(z1); z2 = satz(z2); z3 = satz(z3);
            float ig = fsigm(z0);
            float fg = fsigm(z1);
            float gg = ftanhf(z2);
            float og = fsigm(z3);
            float cnew = fg * creg + ig * gg;
            creg = cnew;
            float hnew = og * ftanhf(satz(cnew));
            unsigned long long w = ((unsigned long long)(unsigned)(s + 1) << 32)
                                 | (unsigned long long)__float_as_uint(hnew);
            __hip_atomic_store(&hb_d[((s + 1) & 1) * HID + j0 + jj], w,
                               __ATOMIC_RELAXED, __HIP_MEMORY_SCOPE_AGENT);
            hso[(size_t)t * HID + j0 + jj] = hnew;
        }
        // no trailing barrier: next iteration's tag-spin is the sync
    }
}

// ---------------------------------------------------------------- outproj + log_softmax + (last block) viterbi
__global__ __launch_bounds__(64) void outproj_kernel(const float* __restrict__ hsout,
        const void* __restrict__ W_out, const void* __restrict__ b_out,
        float* __restrict__ out_scores,
        const void* __restrict__ trans, const void* __restrict__ strans,
        const void* __restrict__ etrans, float* __restrict__ out_path,
        unsigned* __restrict__ vcnt, const int* __restrict__ dflag) {
    __shared__ unsigned char hist[SEQ][NT];
    const int isf32 = *dflag;
    int t = blockIdx.x;
    int lane = threadIdx.x;
    const float* hf = hsout + (size_t)t * HID;
    const float* hb = hsout + (size_t)SEQ * HID + (size_t)t * HID;
    float acc[NT];
#pragma unroll
    for (int j = 0; j < NT; ++j) acc[j] = 0.f;
    for (int k = lane; k < HID; k += 64) {
        float a = hf[k], b2 = hb[k];
#pragma unroll
        for (int j = 0; j < NT; ++j)
            acc[j] += a * ldf(W_out, (size_t)k * NT + j, isf32)
                    + b2 * ldf(W_out, (size_t)(HID + k) * NT + j, isf32);
    }
#pragma unroll
    for (int off = 32; off >= 1; off >>= 1) {
#pragma unroll
        for (int j = 0; j < NT; ++j) acc[j] += __shfl_xor(acc[j], off, 64);
    }
    float o[NT];
    float m = -1e30f;
#pragma unroll
    for (int j = 0; j < NT; ++j) { o[j] = acc[j] + ldf(b_out, j, isf32); m = fmaxf(m, o[j]); }
    float lse = 0.f;
#pragma unroll
    for (int j = 0; j < NT; ++j) lse += expf(o[j] - m);
    lse = m + logf(lse);
    // agent-scope atomic stores -> LLC (visible to the viterbi block without fences)
    if (lane < NT)
        __hip_atomic_store(&out_scores[t * NT + lane], o[lane] - lse,
                           __ATOMIC_RELAXED, __HIP_MEMORY_SCOPE_AGENT);
    __builtin_amdgcn_s_waitcnt(0);   // stores ack'd at LLC before the arrival add

    unsigned old = 0;
    if (lane == 0) old = atomicAdd(vcnt, 1u);
    old = __shfl(old, 0, 64);
    if (old != SEQ - 1) return;

    // ---- last block: all emissions at LLC; run viterbi inline ----
    const float* em = out_scores;
    int j = lane < NT ? lane : 0;
    float tr[NT];
#pragma unroll
    for (int i = 0; i < NT; ++i) tr[i] = ldf(trans, i * NT + j, isf32);
    float score = ldf(strans, j, isf32)
                + __hip_atomic_load(&em[j], __ATOMIC_RELAXED, __HIP_MEMORY_SCOPE_AGENT);
    float pe_next = __hip_atomic_load(&em[NT + j], __ATOMIC_RELAXED, __HIP_MEMORY_SCOPE_AGENT);
    for (int tt = 1; tt < SEQ; ++tt) {
        float pe = pe_next;
        if (tt + 1 < SEQ)
            pe_next = __hip_atomic_load(&em[(tt + 1) * NT + j],
                                        __ATOMIC_RELAXED, __HIP_MEMORY_SCOPE_AGENT);
        float best = -1e30f;
        int arg = 0;
#pragma unroll
        for (int i = 0; i < NT; ++i) {
            float si = __shfl(score, i, 64);
            float cand = si + tr[i];
            if (cand > best) { best = cand; arg = i; }   // strict > == first-index tie-break
        }
        if (lane < NT) hist[tt][lane] = (unsigned char)arg;
        score = best + pe;
    }
    score += ldf(etrans, j, isf32);
    float bmax = -1e30f;
    int last = 0;
#pragma unroll
    for (int i = 0; i < NT; ++i) {
        float si = __shfl(score, i, 64);
        if (si > bmax) { bmax = si; last = i; }
    }
    if (lane == 0) {
        int cur = last;
        out_path[SEQ - 1] = (float)cur;
        for (int tt = SEQ - 1; tt >= 1; --tt) {
            cur = hist[tt][cur];
            out_path[tt - 1] = (float)cur;
        }
    }
}

// ---------------------------------------------------------------- launch
extern "C" void kernel_launch(void* const* d_in, const int* in_sizes, int n_in,
                              void* d_out, int out_size, void* d_ws, size_t ws_size,
                              hipStream_t stream) {
    const int* x      = (const int*)d_in[0];
    const int* casing = (const int*)d_in[1];
    const int* posi   = (const int*)d_in[2];
    const void* h0    = d_in[3];
    const void* c0    = d_in[4];
    const void* W_emb = d_in[5];
    const void* W_cas = d_in[6];
    const void* W_pos = d_in[7];
    const void* Wx_f  = d_in[8];
    const void* Wh_f  = d_in[9];
    const void* b_f   = d_in[10];
    const void* Wx_b  = d_in[11];
    const void* Wh_b  = d_in[12];
    const void* b_b   = d_in[13];
    const void* W_out = d_in[14];
    const void* b_out = d_in[15];
    const void* trans = d_in[16];
    const void* strans = d_in[17];
    const void* etrans = d_in[18];

    // workspace layout (~12.6 MB)
    char* ws = (char*)d_ws;
    int* dflag          = (int*)(ws + 448);
    unsigned* vcnt      = (unsigned*)(ws + 456);
    unsigned short* pre = (unsigned short*)(ws + 512);            // 2*1024*2048 bf16 = 8,388,608
    float* hsout        = (float*)(ws + 512 + 8388608);           // 2*1024*512 f32 = 4,194,304
    unsigned long long* hbuf = (unsigned long long*)(ws + 512 + 8388608 + 4194304); // 2*2*512 u64

    // d_out is FLOAT32: 13312 tag_scores then 1024 path values
    float* out_scores = (float*)d_out;
    float* out_path   = out_scores + SEQ * NT;

    detect_kernel<<<1, 64, 0, stream>>>((const unsigned short*)W_emb, dflag, vcnt);

    dim3 g2(8, 32, 2);
    pre_gemm_kernel<<<g2, 256, 0, stream>>>(x, casing, posi, W_emb, W_cas, W_pos,
                                            Wx_f, b_f, Wx_b, b_b, pre, dflag);

    lstm_kernel<<<2 * NWG_DIR, LSTM_THREADS, 0, stream>>>(
        Wh_f, Wh_b, h0, c0, pre, hsout, hbuf, dflag);

    outproj_kernel<<<SEQ, 64, 0, stream>>>(hsout, W_out, b_out, out_scores,
                                           trans, strans, etrans, out_path, vcnt, dflag);
}

// Round 10
// 2300.573 us; speedup vs baseline: 5.6983x; 1.0952x over previous
//
#include <hip/hip_runtime.h>
#include <hip/hip_bf16.h>
#include <math.h>

#define SEQ 1024
#define HID 512
#define FOURH 2048
#define IND 400
#define NT 13

#define NWG_DIR 32
#define LSTM_THREADS 512
#define JPW 16      // hidden units per WG
#define WCOLS 64    // gate columns per WG (4 gates * 16 units)
#define TAG_INVALID 0xFFFFFFFFu

__device__ __forceinline__ float bf2f(unsigned short u) {
    union { unsigned u32; float f; } v;
    v.u32 = ((unsigned)u) << 16;
    return v.f;
}

__device__ __forceinline__ unsigned short f2bf(float f) {
    union { float f; unsigned u; } v;
    v.f = f;
    unsigned u = v.u;
    unsigned rounding = 0x7FFFu + ((u >> 16) & 1u);
    u += rounding;
    return (unsigned short)(u >> 16);
}

// dtype-agnostic float load: isf32 selects f32 vs bf16 interpretation
__device__ __forceinline__ float ldf(const void* p, size_t i, int isf32) {
    return isf32 ? ((const float*)p)[i] : bf2f(((const unsigned short*)p)[i]);
}

// fast transcendentals: v_exp_f32 / v_rcp_f32 based; abs err ~1e-7
__device__ __forceinline__ float fsigm(float x) {
    return __builtin_amdgcn_rcpf(1.f + __builtin_amdgcn_exp2f(-1.44269504f * x));
}
__device__ __forceinline__ float ftanhf(float x) {
    return 1.f - 2.f * __builtin_amdgcn_rcpf(__builtin_amdgcn_exp2f(2.88539008f * x) + 1.f);
}
// saturating clamp (also squashes NaN from any garbage input)
__device__ __forceinline__ float satz(float z) { return fminf(fmaxf(z, -60.f), 60.f); }

// ---------------------------------------------------------------- input dtype detection + counter zero
__global__ __launch_bounds__(64) void detect_kernel(const unsigned short* __restrict__ w,
                                                    int* __restrict__ flag,
                                                    unsigned* __restrict__ vcnt) {
    int lane = threadIdx.x;
    int cnt = 0;
    for (int i = 0; i < 4; ++i) {
        unsigned short u = w[2 * (lane * 4 + i)];   // low half if buffer is f32
        int e = (u >> 7) & 0xFF;
        if (e >= 90 && e < 127) cnt++;
    }
#pragma unroll
    for (int off = 32; off >= 1; off >>= 1) cnt += __shfl_xor(cnt, off, 64);
    if (lane == 0) *flag = (cnt < 128) ? 1 : 0;    // 1 => inputs are float32
    if (lane == 1) *vcnt = 0;                      // outproj->viterbi completion counter
}

// ---------------------------------------------------------------- pre = feat @ Wx + b (embed fused, both dirs), bf16 out
__global__ __launch_bounds__(256) void pre_gemm_kernel(
        const int* __restrict__ x, const int* __restrict__ cas, const int* __restrict__ pos,
        const void* __restrict__ W_emb, const void* __restrict__ W_cas, const void* __restrict__ W_pos,
        const void* __restrict__ Wx_f, const void* __restrict__ b_f,
        const void* __restrict__ Wx_b, const void* __restrict__ b_b,
        unsigned short* __restrict__ pre, const int* __restrict__ dflag) {
    __shared__ float ftile[32 * IND];    // 51.2 KB
    __shared__ int idxs[96];
    const int isf32 = *dflag;
    int dir = blockIdx.z;
    const void* Wx = dir ? Wx_b : Wx_f;
    const void* bb = dir ? b_b : b_f;
    unsigned short* pre_d = pre + (size_t)dir * SEQ * FOURH;
    int r0 = blockIdx.y * 32;
    int col = blockIdx.x * 256 + threadIdx.x;
    int tid = threadIdx.x;

    if (tid < 32)       idxs[tid] = x[r0 + tid];
    else if (tid < 64)  idxs[tid] = cas[r0 + tid - 32];
    else if (tid < 96)  idxs[tid] = pos[r0 + tid - 64];
    __syncthreads();

    for (int idx = tid; idx < 32 * IND; idx += 256) {
        int r = idx / IND;
        int e = idx - r * IND;
        float v;
        if (e < 300)      v = ldf(W_emb, (size_t)idxs[r] * 300 + e, isf32);
        else if (e < 350) v = ldf(W_cas, (size_t)idxs[32 + r] * 50 + (e - 300), isf32);
        else              v = ldf(W_pos, (size_t)idxs[64 + r] * 50 + (e - 350), isf32);
        ftile[idx] = v;
    }
    __syncthreads();

    float acc[32];
    float bias = ldf(bb, col, isf32);
#pragma unroll
    for (int r = 0; r < 32; ++r) acc[r] = bias;

    if (isf32) {
        const float* W = (const float*)Wx;
        for (int kk = 0; kk < 100; ++kk) {
            int k = kk * 4;
            float w0 = W[(size_t)(k + 0) * FOURH + col];
            float w1 = W[(size_t)(k + 1) * FOURH + col];
            float w2 = W[(size_t)(k + 2) * FOURH + col];
            float w3 = W[(size_t)(k + 3) * FOURH + col];
#pragma unroll
            for (int r = 0; r < 32; ++r) {
                float4 f = *(const float4*)&ftile[r * IND + k];
                acc[r] += f.x * w0 + f.y * w1 + f.z * w2 + f.w * w3;
            }
        }
    } else {
        const unsigned short* W = (const unsigned short*)Wx;
        for (int kk = 0; kk < 100; ++kk) {
            int k = kk * 4;
            float w0 = bf2f(W[(size_t)(k + 0) * FOURH + col]);
            float w1 = bf2f(W[(size_t)(k + 1) * FOURH + col]);
            float w2 = bf2f(W[(size_t)(k + 2) * FOURH + col]);
            float w3 = bf2f(W[(size_t)(k + 3) * FOURH + col]);
#pragma unroll
            for (int r = 0; r < 32; ++r) {
                float4 f = *(const float4*)&ftile[r * IND + k];
                acc[r] += f.x * w0 + f.y * w1 + f.z * w2 + f.w * w3;
            }
        }
    }
    for (int r = 0; r < 32; ++r) pre_d[(size_t)(r0 + r) * FOURH + col] = f2bf(acc[r]);
}

// ---------------------------------------------------------------- persistent bidirectional LSTM
// 64 WGs (32/dir) x 512 threads. Per WG: 64 gate-cols; Wh slice in 16 NAMED float4
// registers (SROA cannot spill named scalars -> guaranteed register residency;
// r9's float[64] array was SROA-rejected and lived in scratch: VGPR_Count=60).
// h exchange: tagged words {f32 value | u32 step tag}, one 8B agent atomic store;
// each wave's lanes spin on exactly its own k-range -> h broadcast via readlane.
// red double-buffered by step parity -> ONE __syncthreads per step.
__global__ __launch_bounds__(LSTM_THREADS, 2) void lstm_kernel(
        const void* __restrict__ Wh_f, const void* __restrict__ Wh_b,
        const void* __restrict__ h0, const void* __restrict__ c0,
        const unsigned short* __restrict__ pre, float* __restrict__ hsout,
        unsigned long long* hbuf, const int* __restrict__ dflag) {
    __shared__ float red[2][8 * WCOLS];  // [parity][seg][unit][gate] partial dots (4 KB)

    const int isf32 = *dflag;
    const int tid = threadIdx.x;
    const int b = blockIdx.x;
    const int dir = b & 1;
    const int g = b >> 1;            // 0..31
    const int j0 = g * JPW;          // 16-unit slice

    const void* Wh = dir ? Wh_b : Wh_f;
    const unsigned short* pre_d = pre + (size_t)dir * SEQ * FOURH;
    float* hso = hsout + (size_t)dir * SEQ * HID;
    unsigned long long* hb_d = hbuf + dir * 2 * HID;   // [parity][512] tagged words

    const int seg  = tid >> 6;          // 0..7 == wave id; k-range seg*64..+63
    const int col  = tid & 63;          // 0..63
    const int unit = col & 15;
    const int gate = col >> 4;
    const int gcol = gate * HID + j0 + unit;
    const int redoff = seg * WCOLS + unit * 4 + gate;

    // ---- stage Wh into 16 NAMED float4 registers ----
    float4 w0, w1, w2, w3, w4, w5, w6, w7, w8, w9, w10, w11, w12, w13, w14, w15;
    if (isf32) {
        const float* wp = (const float*)Wh + (size_t)(seg * 64) * FOURH + gcol;
#define LDW(i) w##i = make_float4(wp[(size_t)(4*i+0)*FOURH], wp[(size_t)(4*i+1)*FOURH], \
                                  wp[(size_t)(4*i+2)*FOURH], wp[(size_t)(4*i+3)*FOURH])
        LDW(0); LDW(1); LDW(2); LDW(3); LDW(4); LDW(5); LDW(6); LDW(7);
        LDW(8); LDW(9); LDW(10); LDW(11); LDW(12); LDW(13); LDW(14); LDW(15);
#undef LDW
    } else {
        const unsigned short* wp = (const unsigned short*)Wh + (size_t)(seg * 64) * FOURH + gcol;
#define LDW(i) w##i = make_float4(bf2f(wp[(size_t)(4*i+0)*FOURH]), bf2f(wp[(size_t)(4*i+1)*FOURH]), \
                                  bf2f(wp[(size_t)(4*i+2)*FOURH]), bf2f(wp[(size_t)(4*i+3)*FOURH]))
        LDW(0); LDW(1); LDW(2); LDW(3); LDW(4); LDW(5); LDW(6); LDW(7);
        LDW(8); LDW(9); LDW(10); LDW(11); LDW(12); LDW(13); LDW(14); LDW(15);
#undef LDW
    }

    float creg = 0.f;
    unsigned short zn0 = 0, zn1 = 0, zn2 = 0, zn3 = 0;   // prefetched pre (bf16)
    if (tid < JPW) {
        creg = ldf(c0, dir * HID + j0 + tid, isf32);
        // init own slice: parity0 = h0 tagged 0, parity1 = INVALID (same-thread
        // same-address program order protects init vs later produce)
        float h0v = ldf(h0, dir * HID + j0 + tid, isf32);
        __hip_atomic_store(&hb_d[j0 + tid],
                           (unsigned long long)__float_as_uint(h0v),
                           __ATOMIC_RELAXED, __HIP_MEMORY_SCOPE_AGENT);
        __hip_atomic_store(&hb_d[HID + j0 + tid],
                           ((unsigned long long)TAG_INVALID << 32),
                           __ATOMIC_RELAXED, __HIP_MEMORY_SCOPE_AGENT);
        int t0 = dir ? (SEQ - 1) : 0;
        zn0 = pre_d[(size_t)t0 * FOURH + 0 * HID + j0 + tid];
        zn1 = pre_d[(size_t)t0 * FOURH + 1 * HID + j0 + tid];
        zn2 = pre_d[(size_t)t0 * FOURH + 2 * HID + j0 + tid];
        zn3 = pre_d[(size_t)t0 * FOURH + 3 * HID + j0 + tid];
    }
    __syncthreads();   // drains vmcnt: own tagged words at LLC before anyone spins

    for (int s = 0; s < SEQ; ++s) {
        const int t = dir ? (SEQ - 1 - s) : s;

        // ---- spin on own tagged word (lane l of wave seg owns k = seg*64+l) ----
        unsigned hu;
        {
            const unsigned long long* wp = &hb_d[(s & 1) * HID + tid];
            const unsigned expect = (unsigned)s;
            unsigned long long w;
            do {
                w = __hip_atomic_load(wp, __ATOMIC_RELAXED, __HIP_MEMORY_SCOPE_AGENT);
            } while ((unsigned)(w >> 32) != expect);
            hu = (unsigned)w;
        }

        // producer lanes: consume prefetched pre, issue next prefetch
        float zc0 = 0.f, zc1 = 0.f, zc2 = 0.f, zc3 = 0.f;
        if (tid < JPW) {
            zc0 = bf2f(zn0); zc1 = bf2f(zn1); zc2 = bf2f(zn2); zc3 = bf2f(zn3);
            if (s + 1 < SEQ) {
                int tn = dir ? (SEQ - 2 - s) : (s + 1);
                zn0 = pre_d[(size_t)tn * FOURH + 0 * HID + j0 + tid];
                zn1 = pre_d[(size_t)tn * FOURH + 1 * HID + j0 + tid];
                zn2 = pre_d[(size_t)tn * FOURH + 2 * HID + j0 + tid];
                zn3 = pre_d[(size_t)tn * FOURH + 3 * HID + j0 + tid];
            }
        }

        // ---- matvec: h broadcast via readlane (no LDS, no barrier) ----
        float a0 = 0.f, a1 = 0.f, a2 = 0.f, a3 = 0.f;
#define MACQ(i, A) { \
        float hx = __uint_as_float((unsigned)__builtin_amdgcn_readlane((int)hu, 4*i+0)); \
        float hy = __uint_as_float((unsigned)__builtin_amdgcn_readlane((int)hu, 4*i+1)); \
        float hz = __uint_as_float((unsigned)__builtin_amdgcn_readlane((int)hu, 4*i+2)); \
        float hw = __uint_as_float((unsigned)__builtin_amdgcn_readlane((int)hu, 4*i+3)); \
        A += hx * w##i.x + hy * w##i.y + hz * w##i.z + hw * w##i.w; }
        MACQ(0, a0)  MACQ(1, a1)  MACQ(2, a2)  MACQ(3, a3)
        MACQ(4, a0)  MACQ(5, a1)  MACQ(6, a2)  MACQ(7, a3)
        MACQ(8, a0)  MACQ(9, a1)  MACQ(10, a2) MACQ(11, a3)
        MACQ(12, a0) MACQ(13, a1) MACQ(14, a2) MACQ(15, a3)
#undef MACQ
        red[s & 1][redoff] = (a0 + a1) + (a2 + a3);
        __syncthreads();   // the ONE barrier: all 8 waves' red(s) complete

        // ---- gates + state update + tagged publish (one quarter-wave) ----
        if (tid < JPW) {
            int jj = tid;
            float z0 = zc0, z1 = zc1, z2 = zc2, z3 = zc3;
            const float* rp = &red[s & 1][0];
#pragma unroll
            for (int s8 = 0; s8 < 8; ++s8) {
                float4 r4 = *(const float4*)&rp[s8 * WCOLS + jj * 4];
                z0 += r4.x; z1 += r4.y; z2 += r4.z; z3 += r4.w;
            }
            z0 = satz(z0); z1 = satz(z1); z2 = satz(z2); z3 = satz(z3);
            float ig = fsigm(z0);
            float fg = fsigm(z1);
            float gg = ftanhf(z2);
            float og = fsigm(z3);
            float cnew = fg * creg + ig * gg;
            creg = cnew;
            float hnew = og * ftanhf(satz(cnew));
            unsigned long long w = ((unsigned long long)(unsigned)(s + 1) << 32)
                                 | (unsigned long long)__float_as_uint(hnew);
            __hip_atomic_store(&hb_d[((s + 1) & 1) * HID + j0 + jj], w,
                               __ATOMIC_RELAXED, __HIP_MEMORY_SCOPE_AGENT);
            hso[(size_t)t * HID + j0 + jj] = hnew;
        }
        // no trailing barrier: next iteration's tag-spin + red parity is the sync
    }
}

// ---------------------------------------------------------------- outproj + log_softmax + (last block) viterbi
__global__ __launch_bounds__(64) void outproj_kernel(const float* __restrict__ hsout,
        const void* __restrict__ W_out, const void* __restrict__ b_out,
        float* __restrict__ out_scores,
        const void* __restrict__ trans, const void* __restrict__ strans,
        const void* __restrict__ etrans, float* __restrict__ out_path,
        unsigned* __restrict__ vcnt, const int* __restrict__ dflag) {
    __shared__ unsigned char hist[SEQ][NT];
    const int isf32 = *dflag;
    int t = blockIdx.x;
    int lane = threadIdx.x;
    const float* hf = hsout + (size_t)t * HID;
    const float* hb = hsout + (size_t)SEQ * HID + (size_t)t * HID;
    float acc[NT];
#pragma unroll
    for (int j = 0; j < NT; ++j) acc[j] = 0.f;
    for (int k = lane; k < HID; k += 64) {
        float a = hf[k], b2 = hb[k];
#pragma unroll
        for (int j = 0; j < NT; ++j)
            acc[j] += a * ldf(W_out, (size_t)k * NT + j, isf32)
                    + b2 * ldf(W_out, (size_t)(HID + k) * NT + j, isf32);
    }
#pragma unroll
    for (int off = 32; off >= 1; off >>= 1) {
#pragma unroll
        for (int j = 0; j < NT; ++j) acc[j] += __shfl_xor(acc[j], off, 64);
    }
    float o[NT];
    float m = -1e30f;
#pragma unroll
    for (int j = 0; j < NT; ++j) { o[j] = acc[j] + ldf(b_out, j, isf32); m = fmaxf(m, o[j]); }
    float lse = 0.f;
#pragma unroll
    for (int j = 0; j < NT; ++j) lse += expf(o[j] - m);
    lse = m + logf(lse);
    // agent-scope atomic stores -> LLC (visible to the viterbi block without fences)
    if (lane < NT)
        __hip_atomic_store(&out_scores[t * NT + lane], o[lane] - lse,
                           __ATOMIC_RELAXED, __HIP_MEMORY_SCOPE_AGENT);
    __builtin_amdgcn_s_waitcnt(0);   // stores ack'd at LLC before the arrival add

    unsigned old = 0;
    if (lane == 0) old = atomicAdd(vcnt, 1u);
    old = __shfl(old, 0, 64);
    if (old != SEQ - 1) return;

    // ---- last block: all emissions at LLC; run viterbi inline (8-deep prefetch) ----
    const float* em = out_scores;
    int j = lane < NT ? lane : 0;
    float tr[NT];
#pragma unroll
    for (int i = 0; i < NT; ++i) tr[i] = ldf(trans, i * NT + j, isf32);
#define EML(tt) __hip_atomic_load(&em[(size_t)(tt) * NT + j], __ATOMIC_RELAXED, __HIP_MEMORY_SCOPE_AGENT)
    float score = ldf(strans, j, isf32) + EML(0);
    float c0 = EML(1), c1 = EML(2), c2 = EML(3), c3 = EML(4),
          c4 = EML(5), c5 = EML(6), c6 = EML(7), c7 = EML(8);
#define VSTEP(PE, TT) { \
    float best = -1e30f; int arg = 0; \
    _Pragma("unroll") \
    for (int i = 0; i < NT; ++i) { \
        float si = __shfl(score, i, 64); \
        float cand = si + tr[i]; \
        if (cand > best) { best = cand; arg = i; } \
    } \
    if (lane < NT) hist[TT][lane] = (unsigned char)arg; \
    score = best + PE; }
    for (int tb = 1; tb < SEQ; tb += 8) {
        int nb = tb + 8;
        float n0 = 0.f, n1 = 0.f, n2 = 0.f, n3 = 0.f, n4 = 0.f, n5 = 0.f, n6 = 0.f, n7 = 0.f;
        if (nb + 0 < SEQ) n0 = EML(nb + 0);
        if (nb + 1 < SEQ) n1 = EML(nb + 1);
        if (nb + 2 < SEQ) n2 = EML(nb + 2);
        if (nb + 3 < SEQ) n3 = EML(nb + 3);
        if (nb + 4 < SEQ) n4 = EML(nb + 4);
        if (nb + 5 < SEQ) n5 = EML(nb + 5);
        if (nb + 6 < SEQ) n6 = EML(nb + 6);
        if (nb + 7 < SEQ) n7 = EML(nb + 7);
        VSTEP(c0, tb + 0)
        if (tb + 1 < SEQ) VSTEP(c1, tb + 1)
        if (tb + 2 < SEQ) VSTEP(c2, tb + 2)
        if (tb + 3 < SEQ) VSTEP(c3, tb + 3)
        if (tb + 4 < SEQ) VSTEP(c4, tb + 4)
        if (tb + 5 < SEQ) VSTEP(c5, tb + 5)
        if (tb + 6 < SEQ) VSTEP(c6, tb + 6)
        if (tb + 7 < SEQ) VSTEP(c7, tb + 7)
        c0 = n0; c1 = n1; c2 = n2; c3 = n3; c4 = n4; c5 = n5; c6 = n6; c7 = n7;
    }
#undef VSTEP
#undef EML
    score += ldf(etrans, j, isf32);
    float bmax = -1e30f;
    int last = 0;
#pragma unroll
    for (int i = 0; i < NT; ++i) {
        float si = __shfl(score, i, 64);
        if (si > bmax) { bmax = si; last = i; }
    }
    if (lane == 0) {
        int cur = last;
        out_path[SEQ - 1] = (float)cur;
        for (int tt = SEQ - 1; tt >= 1; --tt) {
            cur = hist[tt][cur];
            out_path[tt - 1] = (float)cur;
        }
    }
}

// ---------------------------------------------------------------- launch
extern "C" void kernel_launch(void* const* d_in, const int* in_sizes, int n_in,
                              void* d_out, int out_size, void* d_ws, size_t ws_size,
                              hipStream_t stream) {
    const int* x      = (const int*)d_in[0];
    const int* casing = (const int*)d_in[1];
    const int* posi   = (const int*)d_in[2];
    const void* h0    = d_in[3];
    const void* c0    = d_in[4];
    const void* W_emb = d_in[5];
    const void* W_cas = d_in[6];
    const void* W_pos = d_in[7];
    const void* Wx_f  = d_in[8];
    const void* Wh_f  = d_in[9];
    const void* b_f   = d_in[10];
    const void* Wx_b  = d_in[11];
    const void* Wh_b  = d_in[12];
    const void* b_b   = d_in[13];
    const void* W_out = d_in[14];
    const void* b_out = d_in[15];
    const void* trans = d_in[16];
    const void* strans = d_in[17];
    const void* etrans = d_in[18];

    // workspace layout (~12.6 MB)
    char* ws = (char*)d_ws;
    int* dflag          = (int*)(ws + 448);
    unsigned* vcnt      = (unsigned*)(ws + 456);
    unsigned short* pre = (unsigned short*)(ws + 512);            // 2*1024*2048 bf16 = 8,388,608
    float* hsout        = (float*)(ws + 512 + 8388608);           // 2*1024*512 f32 = 4,194,304
    unsigned long long* hbuf = (unsigned long long*)(ws + 512 + 8388608 + 4194304); // 2*2*512 u64

    // d_out is FLOAT32: 13312 tag_scores then 1024 path values
    float* out_scores = (float*)d_out;
    float* out_path   = out_scores + SEQ * NT;

    detect_kernel<<<1, 64, 0, stream>>>((const unsigned short*)W_emb, dflag, vcnt);

    dim3 g2(8, 32, 2);
    pre_gemm_kernel<<<g2, 256, 0, stream>>>(x, casing, posi, W_emb, W_cas, W_pos,
                                            Wx_f, b_f, Wx_b, b_b, pre, dflag);

    lstm_kernel<<<2 * NWG_DIR, LSTM_THREADS, 0, stream>>>(
        Wh_f, Wh_b, h0, c0, pre, hsout, hbuf, dflag);

    outproj_kernel<<<SEQ, 64, 0, stream>>>(hsout, W_out, b_out, out_scores,
                                           trans, strans, etrans, out_path, vcnt, dflag);
}